// Round 9
// baseline (121.512 us; speedup 1.0000x reference)
//
#include <hip/hip_runtime.h>

#define NROW 8192
#define DIM  1447
#define HD   64
#define NCH  48        // 48 k-chunks of 32 (zero-padded 1536)
#define LD65 65        // scan row layout [q][65]

typedef __attribute__((ext_vector_type(8))) short bf16x8;
typedef __attribute__((ext_vector_type(4))) float f32x4;
typedef float f32x4u __attribute__((ext_vector_type(4), aligned(4)));  // 4B-aligned 16B load

__device__ __forceinline__ float lrelu(float v) { return v >= 0.f ? v : 0.01f * v; }

__device__ __forceinline__ unsigned short f2bf(float f) {
  unsigned u = __float_as_uint(f);
  u = u + 0x7fffu + ((u >> 16) & 1u);   // RNE
  return (unsigned short)(u >> 16);
}
__device__ __forceinline__ float bf2f(unsigned short s) {
  return __uint_as_float((unsigned)s << 16);
}

// monotone float<->uint encoding (order-preserving) for atomicMax / sort keys
__device__ __forceinline__ unsigned enc(float f) {
  unsigned u = __float_as_uint(f);
  return (u & 0x80000000u) ? ~u : (u | 0x80000000u);
}
__device__ __forceinline__ float dec(unsigned k) {
  unsigned u = (k & 0x80000000u) ? (k & 0x7fffffffu) : ~k;
  return __uint_as_float(u);
}

__device__ __forceinline__ void cvt_frag(const float* xv, bf16x8& ah, bf16x8& al) {
  union { bf16x8 v; unsigned u[4]; } H, L;
#pragma unroll
  for (int q = 0; q < 4; ++q) {
    unsigned short h0 = f2bf(xv[2 * q]),     h1 = f2bf(xv[2 * q + 1]);
    unsigned short l0 = f2bf(xv[2 * q]     - bf2f(h0));
    unsigned short l1 = f2bf(xv[2 * q + 1] - bf2f(h1));
    H.u[q] = (unsigned)h0 | ((unsigned)h1 << 16);
    L.u[q] = (unsigned)l0 | ((unsigned)l1 << 16);
  }
  ah = H.v; al = L.v;
}

union BU { int4 i; bf16x8 v; };

// K0: block 0: u1/u2/c1/c2 prep + init M1.
// blocks 1..48: W_fc -> bf16 hi/lo in MFMA-fragment-swizzled order:
//   flat[((cg*48 + s)*64 + lane)*8 + e], col = cg*16 + (lane&15),
//   k = s*32 + (lane>>4)*8 + e   (zero-padded past DIM)
__global__ void k_prep(const float* __restrict__ Wtr, const float* __restrict__ btr,
                       const float* __restrict__ a, const float* __restrict__ Wfc,
                       float* __restrict__ u12, unsigned* __restrict__ m1slot,
                       unsigned short* __restrict__ WhS, unsigned short* __restrict__ WlS) {
  int t = threadIdx.x;
  int b = blockIdx.x;
  if (b == 0) {
    if (t < 64) {
      float u1 = 0.f, u2 = 0.f;
      for (int o = 0; o < 64; ++o) {
        float w = Wtr[o * 64 + t];
        u1 += w * a[o];
        u2 += w * a[64 + o];
      }
      u12[t] = u1; u12[64 + t] = u2;
      if (t == 0) {
        float c1 = 0.f, c2 = 0.f;
        for (int o = 0; o < 64; ++o) { c1 += btr[o] * a[o]; c2 += btr[o] * a[64 + o]; }
        u12[128] = c1; u12[129] = c2;
        *m1slot = 0u;
      }
    }
  } else {
    int wi = (b - 1) * 256 + t;           // < 4*48*64 = 12288
    int cg = wi / (NCH * 64);
    int rem = wi - cg * (NCH * 64);
    int s = rem >> 6;
    int l = rem & 63;
    int col = cg * 16 + (l & 15);
    int k0 = s * 32 + (l >> 4) * 8;
    unsigned short hv[8], lv[8];
#pragma unroll
    for (int e = 0; e < 8; ++e) {
      int k = k0 + e;
      float v = (k < DIM) ? Wfc[(size_t)col * DIM + k] : 0.f;
      unsigned short hi = f2bf(v);
      hv[e] = hi;
      lv[e] = f2bf(v - bf2f(hi));
    }
    size_t base = (size_t)wi * 8;
#pragma unroll
    for (int e = 0; e < 8; ++e) { WhS[base + e] = hv[e]; WlS[base + e] = lv[e]; }
  }
}

// K1: partial GEMM, split-bf16 MFMA, LDS-free, barrier-free.
// 2048 blocks (512 rowblocks x 4 K-quarters) x 256 thr (4 colgroup waves).
// 32 waves/CU; 2-deep named-register prefetch; A from x via 2x dwordx4;
// B 1KB-contiguous from pre-swizzled WhS/WlS. Writes f32 partials.
__global__ __launch_bounds__(256, 8) void k_gemm(const float* __restrict__ x,
    const unsigned short* __restrict__ WhS, const unsigned short* __restrict__ WlS,
    float* __restrict__ part) {
  int t = threadIdx.x;
  int cg = t >> 6;           // colgroup 0..3
  int l = t & 63;
  int l15 = l & 15, l4 = l >> 4;
  int bb = blockIdx.x;
  int rb = bb >> 2;          // row block 0..511
  int kq = bb & 3;           // K-quarter
  int R0 = rb * 16;
  int ko = l4 * 8;           // k-octet offset within fragment
  int base = kq * 12;        // first chunk
  int n = (kq == 3) ? 10 : 12;

  const float* xrow = x + (size_t)(R0 + l15) * DIM;
  const unsigned short* whp = WhS + (((size_t)cg * NCH) << 9) + (l << 3);
  const unsigned short* wlp = WlS + (((size_t)cg * NCH) << 9) + (l << 3);

#define LDXQ(S, XB)                                                        \
  do {                                                                     \
    int k0_ = (S) * 32 + ko;                                               \
    if ((S) == NCH - 3) { /* chunk 45: tail mask (W zero-padded past) */   \
      _Pragma("unroll")                                                    \
      for (int e = 0; e < 8; ++e) XB[e] = (k0_ + e < DIM) ? xrow[k0_ + e] : 0.f; \
    } else {                                                               \
      f32x4u a0_ = *(const f32x4u*)(xrow + k0_);                           \
      f32x4u a1_ = *(const f32x4u*)(xrow + k0_ + 4);                       \
      XB[0] = a0_[0]; XB[1] = a0_[1]; XB[2] = a0_[2]; XB[3] = a0_[3];      \
      XB[4] = a1_[0]; XB[5] = a1_[1]; XB[6] = a1_[2]; XB[7] = a1_[3];      \
    }                                                                      \
  } while (0)
#define LDW(S, WH, WL)                                                     \
  do {                                                                     \
    WH = *(const int4*)(whp + ((size_t)(S) << 9));                         \
    WL = *(const int4*)(wlp + ((size_t)(S) << 9));                         \
  } while (0)

  f32x4 acc = {0.f, 0.f, 0.f, 0.f};
  float xA[8], xB[8];
  int4 whA, wlA, whB, wlB;

  LDXQ(base, xA);     LDW(base, whA, wlA);
  LDXQ(base + 1, xB); LDW(base + 1, whB, wlB);

  for (int s = 0; s < n; s += 2) {
    {
      bf16x8 ah, al;
      cvt_frag(xA, ah, al);
      BU bh, bl; bh.i = whA; bl.i = wlA;
      if (s + 2 < n) { LDXQ(base + s + 2, xA); LDW(base + s + 2, whA, wlA); }
      acc = __builtin_amdgcn_mfma_f32_16x16x32_bf16(ah, bh.v, acc, 0, 0, 0);
      acc = __builtin_amdgcn_mfma_f32_16x16x32_bf16(ah, bl.v, acc, 0, 0, 0);
      acc = __builtin_amdgcn_mfma_f32_16x16x32_bf16(al, bh.v, acc, 0, 0, 0);
    }
    {
      bf16x8 ah, al;
      cvt_frag(xB, ah, al);
      BU bh, bl; bh.i = whB; bl.i = wlB;
      if (s + 3 < n) { LDXQ(base + s + 3, xB); LDW(base + s + 3, whB, wlB); }
      acc = __builtin_amdgcn_mfma_f32_16x16x32_bf16(ah, bh.v, acc, 0, 0, 0);
      acc = __builtin_amdgcn_mfma_f32_16x16x32_bf16(ah, bl.v, acc, 0, 0, 0);
      acc = __builtin_amdgcn_mfma_f32_16x16x32_bf16(al, bh.v, acc, 0, 0, 0);
    }
  }
#undef LDXQ
#undef LDW

  // D layout: col = lane&15, row = (lane>>4)*4 + reg  [m89-verified]
  float* pq = part + (size_t)kq * (NROW * HD);
  int col = cg * 16 + l15;
#pragma unroll
  for (int r = 0; r < 4; ++r) {
    int row = R0 + l4 * 4 + r;
    pq[(size_t)row * HD + col] = acc[r];
  }
}

// K1b: h = lrelu(sum_q part[q] + b_fc); fused s1/s2 dots + global max(s1).
// 256 blocks x 256 thr; 32 rows/block; 8 threads/row (8 cols each).
__global__ __launch_bounds__(256) void k_hred(const float* __restrict__ part,
    const float* __restrict__ bfc, const float* __restrict__ u12,
    float* __restrict__ h, float* __restrict__ s1, float* __restrict__ s2,
    unsigned* __restrict__ m1slot) {
  int t = threadIdx.x;
  int r = blockIdx.x * 32 + (t >> 3);
  int cg = t & 7;
  size_t base = (size_t)r * HD + cg * 8;
  float v[8];
#pragma unroll
  for (int j = 0; j < 8; ++j) v[j] = 0.f;
#pragma unroll
  for (int q = 0; q < 4; ++q) {
    const float4* p = (const float4*)&part[(size_t)q * (NROW * HD) + base];
    float4 q0 = p[0], q1 = p[1];
    v[0] += q0.x; v[1] += q0.y; v[2] += q0.z; v[3] += q0.w;
    v[4] += q1.x; v[5] += q1.y; v[6] += q1.z; v[7] += q1.w;
  }
  float d1 = 0.f, d2 = 0.f;
#pragma unroll
  for (int j = 0; j < 8; ++j) {
    int c = cg * 8 + j;
    float hv = lrelu(v[j] + bfc[c]);
    v[j] = hv;
    d1 += hv * u12[c];
    d2 += hv * u12[64 + c];
  }
  float4* hw = (float4*)&h[base];
  hw[0] = make_float4(v[0], v[1], v[2], v[3]);
  hw[1] = make_float4(v[4], v[5], v[6], v[7]);
#pragma unroll
  for (int off = 1; off < 8; off <<= 1) {
    d1 += __shfl_xor(d1, off);
    d2 += __shfl_xor(d2, off);
  }
  float sv1 = d1 + u12[128];
  float sv2 = d2 + u12[129];
  if (cg == 0) { s1[r] = sv1; s2[r] = sv2; }
  float m = sv1;
#pragma unroll
  for (int off = 8; off < 64; off <<= 1) m = fmaxf(m, __shfl_xor(m, off));
  if ((t & 63) == 0) atomicMax(m1slot, enc(m));
}

// K2: exact-rank sort via unique u64 keys (enc(s1)<<13 | j): no ties possible.
// 256 blocks x 512 thr; block owns 32 j's, 4 j's/thread; phased LDS windows.
__global__ __launch_bounds__(512) void k_sort(const float* __restrict__ s1,
                                              float* __restrict__ s1s,
                                              int* __restrict__ inv) {
  __shared__ unsigned long long keys[NROW];  // 64 KB
  __shared__ int lcnt[32];
  int t = threadIdx.x;
#pragma unroll
  for (int i = 0; i < 16; ++i) {
    int j = i * 512 + t;
    keys[j] = ((unsigned long long)enc(s1[j]) << 13) | (unsigned)j;
  }
  if (t < 32) lcnt[t] = 0;
  __syncthreads();
  int jb = blockIdx.x * 32 + (t & 7) * 4;
  unsigned long long k0 = keys[jb], k1 = keys[jb + 1], k2 = keys[jb + 2], k3 = keys[jb + 3];
  int g = t >> 3;  // 0..63, window [g*128, g*128+128)
  int c0 = 0, c1 = 0, c2 = 0, c3 = 0;
#pragma unroll 8
  for (int e = 0; e < 128; ++e) {
    unsigned long long v = keys[g * 128 + ((e + g) & 127)];  // phased: conflict-free
    c0 += (v < k0); c1 += (v < k1); c2 += (v < k2); c3 += (v < k3);
  }
  int js = (t & 7) * 4;
  atomicAdd(&lcnt[js], c0);
  atomicAdd(&lcnt[js + 1], c1);
  atomicAdd(&lcnt[js + 2], c2);
  atomicAdd(&lcnt[js + 3], c3);
  __syncthreads();
  if (t < 32) {
    int r = lcnt[t];
    int j = blockIdx.x * 32 + t;
    inv[r] = j;
    s1s[r] = s1[j];
  }
}

// K3: hsT[c][r] = h[inv[r]][c]  (coalesced gather + LDS transpose)
__global__ __launch_bounds__(256) void k_trans(const float* __restrict__ h,
                                               const int* __restrict__ inv,
                                               float* __restrict__ hsT) {
  __shared__ float tile[64][65];
  int t = threadIdx.x;
  int r0 = blockIdx.x * 64;
  int rr = t >> 2;
  int cseg = (t & 3) * 16;
  int j = inv[r0 + rr];
#pragma unroll
  for (int q = 0; q < 4; ++q) {
    float4 v = *(const float4*)&h[(size_t)j * HD + cseg + q * 4];
    tile[rr][cseg + q * 4]     = v.x;
    tile[rr][cseg + q * 4 + 1] = v.y;
    tile[rr][cseg + q * 4 + 2] = v.z;
    tile[rr][cseg + q * 4 + 3] = v.w;
  }
  __syncthreads();
  int c = t >> 2;
  int rseg = (t & 3) * 16;
#pragma unroll
  for (int e = 0; e < 16; e += 4) {
    int r = rseg + e;
    float4 v = make_float4(tile[r][c], tile[r + 1][c], tile[r + 2][c], tile[r + 3][c]);
    *(float4*)&hsT[(size_t)c * NROW + r0 + r] = v;
  }
}

// K4: per-column prefix(B)/suffix(A) scans over sorted order (float4-streamed),
// output layout [q][65] for coalesced k_final reads.
__global__ __launch_bounds__(512) void k_scan(const float* __restrict__ s1s,
                                              const float* __restrict__ hsT,
                                              const unsigned* __restrict__ m1slot,
                                              float* __restrict__ SufA,
                                              float* __restrict__ PreB) {
  int t = threadIdx.x;
  int c = blockIdx.x % 65;
  int br = blockIdx.x / 65;  // 0 = A (suffix, e^{s1-M1}), 1 = B (prefix, e^{0.01 s1})
  float M1 = dec(*m1slot);
  const float* hc = hsT + (size_t)c * NROW;
  int qb = t * 16;
  int base = br ? qb : (NROW - 16 - qb);   // 16-aligned float4 window
  float sarr[16], harr[16];
#pragma unroll
  for (int m = 0; m < 4; ++m) {
    float4 v = *(const float4*)&s1s[base + m * 4];
    sarr[m * 4] = v.x; sarr[m * 4 + 1] = v.y; sarr[m * 4 + 2] = v.z; sarr[m * 4 + 3] = v.w;
  }
  if (c < 64) {
#pragma unroll
    for (int m = 0; m < 4; ++m) {
      float4 v = *(const float4*)&hc[base + m * 4];
      harr[m * 4] = v.x; harr[m * 4 + 1] = v.y; harr[m * 4 + 2] = v.z; harr[m * 4 + 3] = v.w;
    }
  } else {
#pragma unroll
    for (int m = 0; m < 16; ++m) harr[m] = 1.0f;
  }
  float vals[16];
#pragma unroll
  for (int e = 0; e < 16; ++e) {
    int ridx = br ? e : (15 - e);
    float s = sarr[ridx];
    float w = br ? __expf(0.01f * s) : __expf(s - M1);
    vals[e] = w * harr[ridx];
  }
  float sum = 0.f;
#pragma unroll
  for (int e = 0; e < 16; ++e) sum += vals[e];
  int lane = t & 63, wid = t >> 6;
  float sc = sum;
#pragma unroll
  for (int off = 1; off < 64; off <<= 1) {
    float o = __shfl_up(sc, off);
    if (lane >= off) sc += o;
  }
  __shared__ float wt[8];
  if (lane == 63) wt[wid] = sc;
  __syncthreads();
  float woff = 0.f;
#pragma unroll
  for (int w = 0; w < 8; ++w)
    if (w < wid) woff += wt[w];
  float p = __shfl_up(sc, 1);
  float run = woff + (lane ? p : 0.f);
  if (br) {
#pragma unroll
    for (int e = 0; e < 16; ++e) {
      PreB[(size_t)(qb + e) * LD65 + c] = run;
      run += vals[e];
    }
    if (t == 511) PreB[(size_t)NROW * LD65 + c] = run;  // total
  } else {
#pragma unroll
    for (int e = 0; e < 16; ++e) {
      run += vals[e];
      SufA[(size_t)(NROW - 1 - (qb + e)) * LD65 + c] = run;
    }
    if (t == 0) SufA[(size_t)NROW * LD65 + c] = 0.f;
  }
}

// K5: per-row closed-form softmax combine + residual + W_f/lrelu + W_o.
// 256 blocks x 256 thr; each wave processes 8 rows with Wf row in registers.
__global__ __launch_bounds__(256) void k_final(const float* __restrict__ h,
    const float* __restrict__ s1s, const float* __restrict__ s2,
    const float* __restrict__ SufA, const float* __restrict__ PreB,
    const unsigned* __restrict__ m1slot, const float* __restrict__ Wf,
    const float* __restrict__ bf, const float* __restrict__ Wo,
    const float* __restrict__ bo, float* __restrict__ out) {
  int t = threadIdx.x;
  int lane = t & 63, wid = t >> 6;
  __shared__ float coarse[64];
  if (t < 64) coarse[t] = s1s[t * 128];
  __syncthreads();
  float4 wf[16];
  const float4* wrow = (const float4*)(Wf + (size_t)lane * HD);
#pragma unroll
  for (int q = 0; q < 16; ++q) wf[q] = wrow[q];
  float bfl = bf[lane], wol = Wo[lane], bo0 = bo[0];
  float M1 = dec(*m1slot);
  float myc = coarse[lane];

  for (int rr = 0; rr < 8; ++rr) {
    int i = blockIdx.x * 32 + wid * 8 + rr;
    float s2i = s2[i];
    float th = -s2i;
    float z = s2i + M1;
    float mi = lrelu(z);
    float cA = __expf(z - mi);
    float cB = __expf(0.01f * s2i - mi);
    int n1 = __popcll(__ballot(myc < th));
    int cnt = 0;
    if (n1 > 0) {
      int L = (n1 - 1) * 128;
      float v2 = s1s[L + 1 + 2 * lane];
      int n2 = __popcll(__ballot(v2 < th));
      cnt = L + 2 * n2;
      if (cnt < NROW && s1s[cnt] < th) cnt++;
    }
    const float* ra = SufA + (size_t)cnt * LD65;
    const float* rb = PreB + (size_t)cnt * LD65;
    float vA = ra[lane], vB = rb[lane];
    float zA = ra[64],  zB = rb[64];
    float Z = cA * zA + cB * zB;
    float h2 = (cA * vA + cB * vB) / Z + h[(size_t)i * HD + lane];
    float acc = bfl;
#pragma unroll
    for (int q = 0; q < 16; ++q) {
      float4 wv = wf[q];
      int c = q * 4;
      acc += wv.x * __shfl(h2, c) + wv.y * __shfl(h2, c + 1) +
             wv.z * __shfl(h2, c + 2) + wv.w * __shfl(h2, c + 3);
    }
    float h3 = lrelu(acc);
    float pv = h3 * wol;
#pragma unroll
    for (int off = 32; off > 0; off >>= 1) pv += __shfl_xor(pv, off);
    if (lane == 0) out[i] = pv + bo0;
  }
}

extern "C" void kernel_launch(void* const* d_in, const int* in_sizes, int n_in,
                              void* d_out, int out_size, void* d_ws, size_t ws_size,
                              hipStream_t stream) {
  const float* x   = (const float*)d_in[0];
  const float* Wfc = (const float*)d_in[1];
  const float* bfc = (const float*)d_in[2];
  const float* Wtr = (const float*)d_in[3];
  const float* btr = (const float*)d_in[4];
  const float* a   = (const float*)d_in[5];
  const float* Wf  = (const float*)d_in[6];
  const float* bf  = (const float*)d_in[7];
  const float* Wo  = (const float*)d_in[8];
  const float* bo  = (const float*)d_in[9];
  float* out = (float*)d_out;

  char* w = (char*)d_ws;
  size_t off = 0;
  auto alloc = [&](size_t bytes) -> void* {
    void* p = w + off;
    off = (off + bytes + 255) & ~(size_t)255;
    return p;
  };
  float* h      = (float*)alloc((size_t)NROW * HD * 4);
  float* s1     = (float*)alloc(NROW * 4);
  float* s2     = (float*)alloc(NROW * 4);
  float* u12    = (float*)alloc(130 * 4);
  unsigned* m1  = (unsigned*)alloc(4);
  int* inv      = (int*)alloc(NROW * 4);
  float* s1s    = (float*)alloc(NROW * 4);
  unsigned short* WhS = (unsigned short*)alloc((size_t)4 * NCH * 64 * 8 * 2);
  unsigned short* WlS = (unsigned short*)alloc((size_t)4 * NCH * 64 * 8 * 2);
  float* part   = (float*)alloc((size_t)4 * NROW * HD * 4);   // 8 MB f32 partials
  float* hsT    = (float*)alloc((size_t)HD * NROW * 4);
  float* SufA   = (float*)alloc((size_t)(NROW + 1) * LD65 * 4);
  float* PreB   = (float*)alloc((size_t)(NROW + 1) * LD65 * 4);
  (void)in_sizes; (void)n_in; (void)out_size; (void)ws_size;

  k_prep<<<1 + (4 * NCH * 64) / 256, 256, 0, stream>>>(Wtr, btr, a, Wfc, u12, m1, WhS, WlS);
  k_gemm<<<(NROW / 16) * 4, 256, 0, stream>>>(x, WhS, WlS, part);
  k_hred<<<NROW / 32, 256, 0, stream>>>(part, bfc, u12, h, s1, s2, m1);
  k_sort<<<NROW / 32, 512, 0, stream>>>(s1, s1s, inv);
  k_trans<<<NROW / 64, 256, 0, stream>>>(h, inv, hsT);
  k_scan<<<130, 512, 0, stream>>>(s1s, hsT, m1, SufA, PreB);
  k_final<<<NROW / 32, 256, 0, stream>>>(h, s1s, s2, SufA, PreB, m1, Wf, bf, Wo, bo, out);
}

// Round 10
// 103.971 us; speedup vs baseline: 1.1687x; 1.1687x over previous
//
#include <hip/hip_runtime.h>

#define NROW 8192
#define DIM  1447
#define HD   64
#define NST  46        // k-steps of 32 (zero-padded to 1472)
#define NCHK 12        // 11 full 128-k chunks + 1 tail chunk (64 k)
#define LD65 65        // scan row layout [q][65]

typedef __attribute__((ext_vector_type(8))) short bf16x8;
typedef __attribute__((ext_vector_type(4))) float f32x4;
typedef float f32x4u __attribute__((ext_vector_type(4), aligned(4)));  // 4B-aligned 16B load

__device__ __forceinline__ float lrelu(float v) { return v >= 0.f ? v : 0.01f * v; }

__device__ __forceinline__ unsigned short f2bf(float f) {
  unsigned u = __float_as_uint(f);
  u = u + 0x7fffu + ((u >> 16) & 1u);   // RNE
  return (unsigned short)(u >> 16);
}
__device__ __forceinline__ float bf2f(unsigned short s) {
  return __uint_as_float((unsigned)s << 16);
}

// monotone float<->uint encoding (order-preserving) for atomicMax
__device__ __forceinline__ unsigned enc(float f) {
  unsigned u = __float_as_uint(f);
  return (u & 0x80000000u) ? ~u : (u | 0x80000000u);
}
__device__ __forceinline__ float dec(unsigned k) {
  unsigned u = (k & 0x80000000u) ? (k & 0x7fffffffu) : ~k;
  return __uint_as_float(u);
}

union BU { int4 i; bf16x8 v; };

// K0: block 0: u1/u2/c1/c2 prep + init M1.
// blocks 1..368: W_fc -> bf16 hi/lo in MFMA-fragment-swizzled order:
//   flat[((cg*46 + s)*64 + lane)*8 + e], col = cg*16 + (lane&15),
//   k = s*32 + (lane>>4)*8 + e   (zero-padded past DIM)
__global__ void k_prep(const float* __restrict__ Wtr, const float* __restrict__ btr,
                       const float* __restrict__ a, const float* __restrict__ Wfc,
                       float* __restrict__ u12, unsigned* __restrict__ m1slot,
                       unsigned short* __restrict__ WhS, unsigned short* __restrict__ WlS) {
  int t = threadIdx.x;
  int b = blockIdx.x;
  if (b == 0) {
    if (t < 64) {
      float u1 = 0.f, u2 = 0.f;
      for (int o = 0; o < 64; ++o) {
        float w = Wtr[o * 64 + t];
        u1 += w * a[o];
        u2 += w * a[64 + o];
      }
      u12[t] = u1; u12[64 + t] = u2;
      if (t == 0) {
        float c1 = 0.f, c2 = 0.f;
        for (int o = 0; o < 64; ++o) { c1 += btr[o] * a[o]; c2 += btr[o] * a[64 + o]; }
        u12[128] = c1; u12[129] = c2;
        *m1slot = 0u;
      }
    }
  } else {
    int wi = (b - 1) * 256 + t;           // < 4*46*64 = 11776
    if (wi < 4 * NST * 64) {
      int cg = wi / (NST * 64);
      int rem = wi - cg * (NST * 64);
      int s = rem >> 6;
      int l = rem & 63;
      int col = cg * 16 + (l & 15);
      int k0 = s * 32 + (l >> 4) * 8;
      unsigned short hv[8], lv[8];
#pragma unroll
      for (int e = 0; e < 8; ++e) {
        int k = k0 + e;
        float v = (k < DIM) ? Wfc[(size_t)col * DIM + k] : 0.f;
        unsigned short hi = f2bf(v);
        hv[e] = hi;
        lv[e] = f2bf(v - bf2f(hi));
      }
      size_t base = (size_t)wi * 8;
#pragma unroll
      for (int e = 0; e < 8; ++e) { WhS[base + e] = hv[e]; WlS[base + e] = lv[e]; }
    }
  }
}

// K1: h = lrelu(x @ W_fc.T + b_fc), split-bf16 MFMA.
// 512 blocks x 512 thr; tile 16 rows x 64 cols; 8 waves = 4 colgroups x 2 K-phases.
// x staged LANE-CONTIGUOUSLY in 128-k chunks (f32x4u), converted once to bf16
// hi/lo in LDS (row stride 272B -> even bank spread for b128 frag reads);
// B fragments 1KB-contiguous from pre-swizzled WhS/WlS. Double-buffered,
// 1 barrier/chunk; fused epilogue (Pacc combine + h + s1/s2 + max).
__global__ __launch_bounds__(512, 4) void k_gemm(const float* __restrict__ x,
    const unsigned short* __restrict__ WhS, const unsigned short* __restrict__ WlS,
    const float* __restrict__ bfc, const float* __restrict__ u12,
    float* __restrict__ h, float* __restrict__ s1, float* __restrict__ s2,
    unsigned* __restrict__ m1slot) {
  __shared__ unsigned short XH[2][16][136], XL[2][16][136];  // 17.4 KB
  __shared__ float Pacc[4][16][17];
  __shared__ float Pd1[16][4], Pd2[16][4];
  int t = threadIdx.x;
  int wv = t >> 6;
  int l = t & 63;
  int l15 = l & 15, l4 = l >> 4;
  int cg = wv & 3;           // colgroup 0..3
  int kh = wv >> 2;          // K-phase 0/1 (steps == kh mod 2 within chunk)
  int R0 = blockIdx.x * 16;
  // staging ids: thread -> (row, 4 consecutive k)
  int srow = t >> 5;         // 0..15
  int skl = (t & 31) * 4;    // 0..124

  const float* xst = x + (size_t)(R0 + srow) * DIM;
  const unsigned short* whp = WhS + (((size_t)cg * NST) << 9) + (l << 3);
  const unsigned short* wlp = WlS + (((size_t)cg * NST) << 9) + (l << 3);

  float xr0, xr1, xr2, xr3;

#define STLOAD(C)                                                          \
  do {                                                                     \
    int kg_ = (C) * 128 + skl;                                             \
    if ((C) < 11) {                                                        \
      f32x4u v_ = *(const f32x4u*)(xst + kg_);                             \
      xr0 = v_[0]; xr1 = v_[1]; xr2 = v_[2]; xr3 = v_[3];                  \
    } else {                                                               \
      xr0 = (kg_     < DIM) ? xst[kg_]     : 0.f;                          \
      xr1 = (kg_ + 1 < DIM) ? xst[kg_ + 1] : 0.f;                          \
      xr2 = (kg_ + 2 < DIM) ? xst[kg_ + 2] : 0.f;                          \
      xr3 = (kg_ + 3 < DIM) ? xst[kg_ + 3] : 0.f;                          \
    }                                                                      \
  } while (0)

#define STWRITE(B)                                                         \
  do {                                                                     \
    unsigned short h0_ = f2bf(xr0), h1_ = f2bf(xr1),                       \
                   h2_ = f2bf(xr2), h3_ = f2bf(xr3);                       \
    unsigned short m0_ = f2bf(xr0 - bf2f(h0_)), m1_ = f2bf(xr1 - bf2f(h1_)), \
                   m2_ = f2bf(xr2 - bf2f(h2_)), m3_ = f2bf(xr3 - bf2f(h3_)); \
    uint2 ph_, pl_;                                                        \
    ph_.x = (unsigned)h0_ | ((unsigned)h1_ << 16);                         \
    ph_.y = (unsigned)h2_ | ((unsigned)h3_ << 16);                         \
    pl_.x = (unsigned)m0_ | ((unsigned)m1_ << 16);                         \
    pl_.y = (unsigned)m2_ | ((unsigned)m3_ << 16);                         \
    *(uint2*)&XH[B][srow][skl] = ph_;                                      \
    *(uint2*)&XL[B][srow][skl] = pl_;                                      \
  } while (0)

  f32x4 acc = {0.f, 0.f, 0.f, 0.f};

  STLOAD(0);
  STWRITE(0);
  __syncthreads();

  for (int c = 0; c < NCHK; ++c) {
    int buf = c & 1;
    if (c + 1 < NCHK) STLOAD(c + 1);
    int nloc = (c == 11) ? 1 : 2;
    for (int ii = 0; ii < nloc; ++ii) {
      int sl = kh + ii * 2;            // local step in chunk
      int sg = c * 4 + sl;             // global k-step
      BU bh, bl;
      bh.i = *(const int4*)(whp + ((size_t)sg << 9));
      bl.i = *(const int4*)(wlp + ((size_t)sg << 9));
      bf16x8 ah = *(const bf16x8*)&XH[buf][l15][sl * 32 + l4 * 8];
      bf16x8 al = *(const bf16x8*)&XL[buf][l15][sl * 32 + l4 * 8];
      acc = __builtin_amdgcn_mfma_f32_16x16x32_bf16(ah, bh.v, acc, 0, 0, 0);
      acc = __builtin_amdgcn_mfma_f32_16x16x32_bf16(ah, bl.v, acc, 0, 0, 0);
      acc = __builtin_amdgcn_mfma_f32_16x16x32_bf16(al, bh.v, acc, 0, 0, 0);
    }
    if (c + 1 < NCHK) STWRITE(buf ^ 1);
    __syncthreads();
  }
#undef STLOAD
#undef STWRITE

  // epilogue: combine K-phases, bias + lrelu + h store, fused s1/s2 + max.
  // D layout: col = lane&15, row = (lane>>4)*4 + reg  [m89-verified]
  if (kh == 1) {
#pragma unroll
    for (int r = 0; r < 4; ++r) Pacc[cg][l4 * 4 + r][l15] = acc[r];
  }
  __syncthreads();
  if (kh == 0) {
    int col = cg * 16 + l15;
    float bb = bfc[col];
    float u1c = u12[col], u2c = u12[64 + col];
#pragma unroll
    for (int r = 0; r < 4; ++r) {
      int rl = l4 * 4 + r;
      float hv = lrelu(acc[r] + Pacc[cg][rl][l15] + bb);
      h[(size_t)(R0 + rl) * HD + col] = hv;
      float d1 = hv * u1c, d2 = hv * u2c;
      d1 += __shfl_xor(d1, 1); d1 += __shfl_xor(d1, 2);
      d1 += __shfl_xor(d1, 4); d1 += __shfl_xor(d1, 8);
      d2 += __shfl_xor(d2, 1); d2 += __shfl_xor(d2, 2);
      d2 += __shfl_xor(d2, 4); d2 += __shfl_xor(d2, 8);
      if (l15 == 0) { Pd1[rl][cg] = d1; Pd2[rl][cg] = d2; }
    }
  }
  __syncthreads();
  if (t < 16) {
    float d1 = Pd1[t][0] + Pd1[t][1] + Pd1[t][2] + Pd1[t][3] + u12[128];
    float d2 = Pd2[t][0] + Pd2[t][1] + Pd2[t][2] + Pd2[t][3] + u12[129];
    int gr = R0 + t;
    s1[gr] = d1;
    s2[gr] = d2;
    float m = d1;
    m = fmaxf(m, __shfl_xor(m, 1));
    m = fmaxf(m, __shfl_xor(m, 2));
    m = fmaxf(m, __shfl_xor(m, 4));
    m = fmaxf(m, __shfl_xor(m, 8));
    if (t == 0) atomicMax(m1slot, enc(m));
  }
}

// K2: exact-rank sort, f32 keys + index tie-break, float4 LDS reads (bank-phased).
// 256 blocks x 512 thr; block owns 32 j's; 16 threads/j, 512 compares each.
__global__ __launch_bounds__(512) void k_sort(const float* __restrict__ s1,
                                              float* __restrict__ s1s,
                                              int* __restrict__ inv) {
  __shared__ alignas(16) float sv[NROW];  // 32 KB
  int t = threadIdx.x;
#pragma unroll
  for (int i = 0; i < 16; ++i) sv[i * 512 + t] = s1[i * 512 + t];
  __syncthreads();
  int jl = t >> 4, sub = t & 15;
  int j = blockIdx.x * 32 + jl;
  float my = sv[j];
  int base = sub * 512;
  int cnt = 0;
#pragma unroll 4
  for (int e = 0; e < 128; ++e) {
    int off = ((e + sub * 9) & 127) * 4;   // phase per sub: 2-way banks (free)
    int i0 = base + off;
    float4 v = *(const float4*)&sv[i0];
    cnt += (v.x < my) + (v.y < my) + (v.z < my) + (v.w < my);
    cnt += (v.x == my && i0 < j) + (v.y == my && i0 + 1 < j) +
           (v.z == my && i0 + 2 < j) + (v.w == my && i0 + 3 < j);
  }
  cnt += __shfl_xor(cnt, 1);
  cnt += __shfl_xor(cnt, 2);
  cnt += __shfl_xor(cnt, 4);
  cnt += __shfl_xor(cnt, 8);
  if (sub == 0) { inv[cnt] = j; s1s[cnt] = my; }
}

// K3: hsT[c][r] = h[inv[r]][c]  (coalesced gather + LDS transpose), 256 blocks.
__global__ __launch_bounds__(256) void k_trans(const float* __restrict__ h,
                                               const int* __restrict__ inv,
                                               float* __restrict__ hsT) {
  __shared__ float tile[32][65];
  int t = threadIdx.x;
  int r0 = blockIdx.x * 32;
  int rr = t >> 3;
  int cseg = (t & 7) * 8;
  int j = inv[r0 + rr];
#pragma unroll
  for (int q = 0; q < 2; ++q) {
    float4 v = *(const float4*)&h[(size_t)j * HD + cseg + q * 4];
    tile[rr][cseg + q * 4]     = v.x;
    tile[rr][cseg + q * 4 + 1] = v.y;
    tile[rr][cseg + q * 4 + 2] = v.z;
    tile[rr][cseg + q * 4 + 3] = v.w;
  }
  __syncthreads();
  int c = t >> 2;
  int rseg = (t & 3) * 8;
#pragma unroll
  for (int e = 0; e < 8; e += 4) {
    int r = rseg + e;
    float4 v = make_float4(tile[r][c], tile[r + 1][c], tile[r + 2][c], tile[r + 3][c]);
    *(float4*)&hsT[(size_t)c * NROW + r0 + r] = v;
  }
}

// K4: per-column prefix(B)/suffix(A) scans over sorted order (float4-streamed),
// output layout [q][65] for coalesced k_final reads.
__global__ __launch_bounds__(512) void k_scan(const float* __restrict__ s1s,
                                              const float* __restrict__ hsT,
                                              const unsigned* __restrict__ m1slot,
                                              float* __restrict__ SufA,
                                              float* __restrict__ PreB) {
  int t = threadIdx.x;
  int c = blockIdx.x % 65;
  int br = blockIdx.x / 65;  // 0 = A (suffix, e^{s1-M1}), 1 = B (prefix, e^{0.01 s1})
  float M1 = dec(*m1slot);
  const float* hc = hsT + (size_t)c * NROW;
  int qb = t * 16;
  int base = br ? qb : (NROW - 16 - qb);   // 16-aligned float4 window
  float sarr[16], harr[16];
#pragma unroll
  for (int m = 0; m < 4; ++m) {
    float4 v = *(const float4*)&s1s[base + m * 4];
    sarr[m * 4] = v.x; sarr[m * 4 + 1] = v.y; sarr[m * 4 + 2] = v.z; sarr[m * 4 + 3] = v.w;
  }
  if (c < 64) {
#pragma unroll
    for (int m = 0; m < 4; ++m) {
      float4 v = *(const float4*)&hc[base + m * 4];
      harr[m * 4] = v.x; harr[m * 4 + 1] = v.y; harr[m * 4 + 2] = v.z; harr[m * 4 + 3] = v.w;
    }
  } else {
#pragma unroll
    for (int m = 0; m < 16; ++m) harr[m] = 1.0f;
  }
  float vals[16];
#pragma unroll
  for (int e = 0; e < 16; ++e) {
    int ridx = br ? e : (15 - e);
    float s = sarr[ridx];
    float w = br ? __expf(0.01f * s) : __expf(s - M1);
    vals[e] = w * harr[ridx];
  }
  float sum = 0.f;
#pragma unroll
  for (int e = 0; e < 16; ++e) sum += vals[e];
  int lane = t & 63, wid = t >> 6;
  float sc = sum;
#pragma unroll
  for (int off = 1; off < 64; off <<= 1) {
    float o = __shfl_up(sc, off);
    if (lane >= off) sc += o;
  }
  __shared__ float wt[8];
  if (lane == 63) wt[wid] = sc;
  __syncthreads();
  float woff = 0.f;
#pragma unroll
  for (int w = 0; w < 8; ++w)
    if (w < wid) woff += wt[w];
  float p = __shfl_up(sc, 1);
  float run = woff + (lane ? p : 0.f);
  if (br) {
#pragma unroll
    for (int e = 0; e < 16; ++e) {
      PreB[(size_t)(qb + e) * LD65 + c] = run;
      run += vals[e];
    }
    if (t == 511) PreB[(size_t)NROW * LD65 + c] = run;  // total
  } else {
#pragma unroll
    for (int e = 0; e < 16; ++e) {
      run += vals[e];
      SufA[(size_t)(NROW - 1 - (qb + e)) * LD65 + c] = run;
    }
    if (t == 0) SufA[(size_t)NROW * LD65 + c] = 0.f;
  }
}

// K5: per-row closed-form softmax combine + residual + W_f/lrelu + W_o.
// 256 blocks x 256 thr; each wave processes 8 rows with Wf row in registers.
__global__ __launch_bounds__(256) void k_final(const float* __restrict__ h,
    const float* __restrict__ s1s, const float* __restrict__ s2,
    const float* __restrict__ SufA, const float* __restrict__ PreB,
    const unsigned* __restrict__ m1slot, const float* __restrict__ Wf,
    const float* __restrict__ bf, const float* __restrict__ Wo,
    const float* __restrict__ bo, float* __restrict__ out) {
  int t = threadIdx.x;
  int lane = t & 63, wid = t >> 6;
  __shared__ float coarse[64];
  if (t < 64) coarse[t] = s1s[t * 128];
  __syncthreads();
  float4 wf[16];
  const float4* wrow = (const float4*)(Wf + (size_t)lane * HD);
#pragma unroll
  for (int q = 0; q < 16; ++q) wf[q] = wrow[q];
  float bfl = bf[lane], wol = Wo[lane], bo0 = bo[0];
  float M1 = dec(*m1slot);
  float myc = coarse[lane];

  for (int rr = 0; rr < 8; ++rr) {
    int i = blockIdx.x * 32 + wid * 8 + rr;
    float s2i = s2[i];
    float th = -s2i;
    float z = s2i + M1;
    float mi = lrelu(z);
    float cA = __expf(z - mi);
    float cB = __expf(0.01f * s2i - mi);
    int n1 = __popcll(__ballot(myc < th));
    int cnt = 0;
    if (n1 > 0) {
      int L = (n1 - 1) * 128;
      float v2 = s1s[L + 1 + 2 * lane];
      int n2 = __popcll(__ballot(v2 < th));
      cnt = L + 2 * n2;
      if (cnt < NROW && s1s[cnt] < th) cnt++;
    }
    const float* ra = SufA + (size_t)cnt * LD65;
    const float* rb = PreB + (size_t)cnt * LD65;
    float vA = ra[lane], vB = rb[lane];
    float zA = ra[64],  zB = rb[64];
    float Z = cA * zA + cB * zB;
    float h2 = (cA * vA + cB * vB) / Z + h[(size_t)i * HD + lane];
    float acc = bfl;
#pragma unroll
    for (int q = 0; q < 16; ++q) {
      float4 wv = wf[q];
      int c = q * 4;
      acc += wv.x * __shfl(h2, c) + wv.y * __shfl(h2, c + 1) +
             wv.z * __shfl(h2, c + 2) + wv.w * __shfl(h2, c + 3);
    }
    float h3 = lrelu(acc);
    float pv = h3 * wol;
#pragma unroll
    for (int off = 32; off > 0; off >>= 1) pv += __shfl_xor(pv, off);
    if (lane == 0) out[i] = pv + bo0;
  }
}

extern "C" void kernel_launch(void* const* d_in, const int* in_sizes, int n_in,
                              void* d_out, int out_size, void* d_ws, size_t ws_size,
                              hipStream_t stream) {
  const float* x   = (const float*)d_in[0];
  const float* Wfc = (const float*)d_in[1];
  const float* bfc = (const float*)d_in[2];
  const float* Wtr = (const float*)d_in[3];
  const float* btr = (const float*)d_in[4];
  const float* a   = (const float*)d_in[5];
  const float* Wf  = (const float*)d_in[6];
  const float* bf  = (const float*)d_in[7];
  const float* Wo  = (const float*)d_in[8];
  const float* bo  = (const float*)d_in[9];
  float* out = (float*)d_out;

  char* w = (char*)d_ws;
  size_t off = 0;
  auto alloc = [&](size_t bytes) -> void* {
    void* p = w + off;
    off = (off + bytes + 255) & ~(size_t)255;
    return p;
  };
  float* h      = (float*)alloc((size_t)NROW * HD * 4);
  float* s1     = (float*)alloc(NROW * 4);
  float* s2     = (float*)alloc(NROW * 4);
  float* u12    = (float*)alloc(130 * 4);
  unsigned* m1  = (unsigned*)alloc(4);
  int* inv      = (int*)alloc(NROW * 4);
  float* s1s    = (float*)alloc(NROW * 4);
  unsigned short* WhS = (unsigned short*)alloc((size_t)4 * NST * 64 * 8 * 2);
  unsigned short* WlS = (unsigned short*)alloc((size_t)4 * NST * 64 * 8 * 2);
  float* hsT    = (float*)alloc((size_t)HD * NROW * 4);
  float* SufA   = (float*)alloc((size_t)(NROW + 1) * LD65 * 4);
  float* PreB   = (float*)alloc((size_t)(NROW + 1) * LD65 * 4);
  (void)in_sizes; (void)n_in; (void)out_size; (void)ws_size;

  k_prep<<<1 + (4 * NST * 64 + 255) / 256, 256, 0, stream>>>(Wtr, btr, a, Wfc, u12, m1, WhS, WlS);
  k_gemm<<<NROW / 16, 512, 0, stream>>>(x, WhS, WlS, bfc, u12, h, s1, s2, m1);
  k_sort<<<NROW / 32, 512, 0, stream>>>(s1, s1s, inv);
  k_trans<<<NROW / 32, 256, 0, stream>>>(h, inv, hsT);
  k_scan<<<130, 512, 0, stream>>>(s1s, hsT, m1, SufA, PreB);
  k_final<<<NROW / 32, 256, 0, stream>>>(h, s1s, s2, SufA, PreB, m1, Wf, bf, Wo, bo, out);
}

// Round 11
// 92.484 us; speedup vs baseline: 1.3139x; 1.1242x over previous
//
#include <hip/hip_runtime.h>

#define NROW 8192
#define DIM  1447
#define HD   64
#define NCH  48        // 48 k-chunks of 32 (zero-padded 1536); steps 46..47 unused
#define LD65 65        // scan row layout [q][65]

typedef __attribute__((ext_vector_type(8))) short bf16x8;
typedef __attribute__((ext_vector_type(4))) float f32x4;
typedef float f32x4u __attribute__((ext_vector_type(4), aligned(4)));  // 4B-aligned 16B load

__device__ __forceinline__ float lrelu(float v) { return v >= 0.f ? v : 0.01f * v; }

__device__ __forceinline__ unsigned short f2bf(float f) {
  unsigned u = __float_as_uint(f);
  u = u + 0x7fffu + ((u >> 16) & 1u);   // RNE
  return (unsigned short)(u >> 16);
}
__device__ __forceinline__ float bf2f(unsigned short s) {
  return __uint_as_float((unsigned)s << 16);
}

// monotone float<->uint encoding (order-preserving) for atomicMax / sort keys
__device__ __forceinline__ unsigned enc(float f) {
  unsigned u = __float_as_uint(f);
  return (u & 0x80000000u) ? ~u : (u | 0x80000000u);
}
__device__ __forceinline__ float dec(unsigned k) {
  unsigned u = (k & 0x80000000u) ? (k & 0x7fffffffu) : ~k;
  return __uint_as_float(u);
}

__device__ __forceinline__ void cvt_frag(const float* xv, bf16x8& ah, bf16x8& al) {
  union { bf16x8 v; unsigned u[4]; } H, L;
#pragma unroll
  for (int q = 0; q < 4; ++q) {
    unsigned short h0 = f2bf(xv[2 * q]),     h1 = f2bf(xv[2 * q + 1]);
    unsigned short l0 = f2bf(xv[2 * q]     - bf2f(h0));
    unsigned short l1 = f2bf(xv[2 * q + 1] - bf2f(h1));
    H.u[q] = (unsigned)h0 | ((unsigned)h1 << 16);
    L.u[q] = (unsigned)l0 | ((unsigned)l1 << 16);
  }
  ah = H.v; al = L.v;
}

union BU { int4 i; bf16x8 v; };

// K0: block 0: u1/u2/c1/c2 prep + init M1.
// blocks 1..48: W_fc -> bf16 hi/lo in MFMA-fragment-swizzled order:
//   flat[((cg*48 + s)*64 + lane)*8 + e], col = cg*16 + (lane&15),
//   k = s*32 + (lane>>4)*8 + e   (zero-padded past DIM)
__global__ void k_prep(const float* __restrict__ Wtr, const float* __restrict__ btr,
                       const float* __restrict__ a, const float* __restrict__ Wfc,
                       float* __restrict__ u12, unsigned* __restrict__ m1slot,
                       unsigned short* __restrict__ WhS, unsigned short* __restrict__ WlS) {
  int t = threadIdx.x;
  int b = blockIdx.x;
  if (b == 0) {
    if (t < 64) {
      float u1 = 0.f, u2 = 0.f;
      for (int o = 0; o < 64; ++o) {
        float w = Wtr[o * 64 + t];
        u1 += w * a[o];
        u2 += w * a[64 + o];
      }
      u12[t] = u1; u12[64 + t] = u2;
      if (t == 0) {
        float c1 = 0.f, c2 = 0.f;
        for (int o = 0; o < 64; ++o) { c1 += btr[o] * a[o]; c2 += btr[o] * a[64 + o]; }
        u12[128] = c1; u12[129] = c2;
        *m1slot = 0u;
      }
    }
  } else {
    int wi = (b - 1) * 256 + t;           // < 4*48*64 = 12288
    int cg = wi / (NCH * 64);
    int rem = wi - cg * (NCH * 64);
    int s = rem >> 6;
    int l = rem & 63;
    int col = cg * 16 + (l & 15);
    int k0 = s * 32 + (l >> 4) * 8;
    unsigned short hv[8], lv[8];
#pragma unroll
    for (int e = 0; e < 8; ++e) {
      int k = k0 + e;
      float v = (k < DIM) ? Wfc[(size_t)col * DIM + k] : 0.f;
      unsigned short hi = f2bf(v);
      hv[e] = hi;
      lv[e] = f2bf(v - bf2f(hi));
    }
    size_t base = (size_t)wi * 8;
#pragma unroll
    for (int e = 0; e < 8; ++e) { WhS[base + e] = hv[e]; WlS[base + e] = lv[e]; }
  }
}

// K1: h = lrelu(x @ W_fc.T + b_fc), split-bf16 MFMA, LDS-free, barrier-free,
// FULLY UNROLLED 46-step K-loop (compile-time) -> compiler hoists 10+ steps of
// independent loads (deep MLP) under counted vmcnt. 512 blocks x 4 waves;
// wave owns one 16x16 tile-column; A via 2x dwordx4 from x, B 1KB-contiguous
// from pre-swizzled WhS/WlS. Fused s1/s2/max epilogue.
__global__ __launch_bounds__(256, 2) void k_gemm(const float* __restrict__ x,
    const unsigned short* __restrict__ WhS, const unsigned short* __restrict__ WlS,
    const float* __restrict__ bfc, const float* __restrict__ u12,
    float* __restrict__ h, float* __restrict__ s1, float* __restrict__ s2,
    unsigned* __restrict__ m1slot) {
  __shared__ float Pd1[16][4], Pd2[16][4];
  int t = threadIdx.x;
  int cg = t >> 6;           // colgroup 0..3
  int l = t & 63;
  int l15 = l & 15, l4 = l >> 4;
  int R0 = blockIdx.x * 16;
  int ko = l4 * 8;           // k-octet offset within fragment

  const float* xrow = x + (size_t)(R0 + l15) * DIM;
  const unsigned short* whp = WhS + (((size_t)cg * NCH) << 9) + (l << 3);
  const unsigned short* wlp = WlS + (((size_t)cg * NCH) << 9) + (l << 3);

  f32x4 acc = {0.f, 0.f, 0.f, 0.f};

#pragma unroll
  for (int s = 0; s < 46; ++s) {
    float xv[8];
    if (s < 45) {
      f32x4u a0 = *(const f32x4u*)(xrow + s * 32 + ko);
      f32x4u a1 = *(const f32x4u*)(xrow + s * 32 + ko + 4);
      xv[0] = a0[0]; xv[1] = a0[1]; xv[2] = a0[2]; xv[3] = a0[3];
      xv[4] = a1[0]; xv[5] = a1[1]; xv[6] = a1[2]; xv[7] = a1[3];
    } else {  // s == 45: tail mask (compile-time branch; W zero-padded past DIM)
      int k0 = s * 32 + ko;
#pragma unroll
      for (int e = 0; e < 8; ++e) xv[e] = (k0 + e < DIM) ? xrow[k0 + e] : 0.f;
    }
    bf16x8 ah, al;
    cvt_frag(xv, ah, al);
    BU bh, bl;
    bh.i = *(const int4*)(whp + ((size_t)s << 9));
    bl.i = *(const int4*)(wlp + ((size_t)s << 9));
    acc = __builtin_amdgcn_mfma_f32_16x16x32_bf16(ah, bh.v, acc, 0, 0, 0);
    acc = __builtin_amdgcn_mfma_f32_16x16x32_bf16(ah, bl.v, acc, 0, 0, 0);
    acc = __builtin_amdgcn_mfma_f32_16x16x32_bf16(al, bh.v, acc, 0, 0, 0);
  }

  // epilogue: bias + lrelu + store h; fused partial s1/s2 dots.
  // D layout: col = lane&15, row = (lane>>4)*4 + reg  [m89-verified]
  int col = cg * 16 + l15;
  float bb = bfc[col];
  float u1c = u12[col], u2c = u12[64 + col];
#pragma unroll
  for (int r = 0; r < 4; ++r) {
    int rl = l4 * 4 + r;
    float hv = lrelu(acc[r] + bb);
    h[(size_t)(R0 + rl) * HD + col] = hv;
    float d1 = hv * u1c, d2 = hv * u2c;
    d1 += __shfl_xor(d1, 1); d1 += __shfl_xor(d1, 2);
    d1 += __shfl_xor(d1, 4); d1 += __shfl_xor(d1, 8);
    d2 += __shfl_xor(d2, 1); d2 += __shfl_xor(d2, 2);
    d2 += __shfl_xor(d2, 4); d2 += __shfl_xor(d2, 8);
    if (l15 == 0) { Pd1[rl][cg] = d1; Pd2[rl][cg] = d2; }
  }
  __syncthreads();
  if (t < 16) {
    float d1 = Pd1[t][0] + Pd1[t][1] + Pd1[t][2] + Pd1[t][3] + u12[128];
    float d2 = Pd2[t][0] + Pd2[t][1] + Pd2[t][2] + Pd2[t][3] + u12[129];
    int gr = R0 + t;
    s1[gr] = d1;
    s2[gr] = d2;
    float m = d1;
    m = fmaxf(m, __shfl_xor(m, 1));
    m = fmaxf(m, __shfl_xor(m, 2));
    m = fmaxf(m, __shfl_xor(m, 4));
    m = fmaxf(m, __shfl_xor(m, 8));
    if (t == 0) atomicMax(m1slot, enc(m));
  }
}

// K2: exact-rank sort via unique u64 keys (enc(s1)<<13 | j): no ties possible,
// 2-op compares. 256 blocks x 512 thr; block owns 32 j's, 4 j's per thread
// (register-tiled), 64 scan-groups of 128 elements; LDS-atomic combine.
__global__ __launch_bounds__(512) void k_sort(const float* __restrict__ s1,
                                              float* __restrict__ s1s,
                                              int* __restrict__ inv) {
  __shared__ unsigned long long keys[NROW];  // 64 KB
  __shared__ int lcnt[32];
  int t = threadIdx.x;
#pragma unroll
  for (int i = 0; i < 16; ++i) {
    int j = i * 512 + t;
    keys[j] = ((unsigned long long)enc(s1[j]) << 13) | (unsigned)j;
  }
  if (t < 32) lcnt[t] = 0;
  __syncthreads();
  int jb = blockIdx.x * 32 + (t & 7) * 4;
  unsigned long long k0 = keys[jb], k1 = keys[jb + 1], k2 = keys[jb + 2], k3 = keys[jb + 3];
  int g = t >> 3;  // 0..63, window [g*128, g*128+128)
  int c0 = 0, c1 = 0, c2 = 0, c3 = 0;
#pragma unroll 8
  for (int e = 0; e < 128; ++e) {
    unsigned long long v = keys[g * 128 + ((e + g) & 127)];  // phased: conflict-free
    c0 += (v < k0); c1 += (v < k1); c2 += (v < k2); c3 += (v < k3);
  }
  int js = (t & 7) * 4;
  atomicAdd(&lcnt[js], c0);
  atomicAdd(&lcnt[js + 1], c1);
  atomicAdd(&lcnt[js + 2], c2);
  atomicAdd(&lcnt[js + 3], c3);
  __syncthreads();
  if (t < 32) {
    int r = lcnt[t];
    int j = blockIdx.x * 32 + t;
    inv[r] = j;
    s1s[r] = s1[j];
  }
}

// K3: hsT[c][r] = h[inv[r]][c]  (coalesced gather + LDS transpose)
__global__ __launch_bounds__(256) void k_trans(const float* __restrict__ h,
                                               const int* __restrict__ inv,
                                               float* __restrict__ hsT) {
  __shared__ float tile[64][65];
  int t = threadIdx.x;
  int r0 = blockIdx.x * 64;
  int rr = t >> 2;
  int cseg = (t & 3) * 16;
  int j = inv[r0 + rr];
#pragma unroll
  for (int q = 0; q < 4; ++q) {
    float4 v = *(const float4*)&h[(size_t)j * HD + cseg + q * 4];
    tile[rr][cseg + q * 4]     = v.x;
    tile[rr][cseg + q * 4 + 1] = v.y;
    tile[rr][cseg + q * 4 + 2] = v.z;
    tile[rr][cseg + q * 4 + 3] = v.w;
  }
  __syncthreads();
  int c = t >> 2;
  int rseg = (t & 3) * 16;
#pragma unroll
  for (int e = 0; e < 16; e += 4) {
    int r = rseg + e;
    float4 v = make_float4(tile[r][c], tile[r + 1][c], tile[r + 2][c], tile[r + 3][c]);
    *(float4*)&hsT[(size_t)c * NROW + r0 + r] = v;
  }
}

// K4: per-column prefix(B)/suffix(A) scans over sorted order (float4-streamed),
// output layout [q][65] for coalesced k_final reads.
__global__ __launch_bounds__(512) void k_scan(const float* __restrict__ s1s,
                                              const float* __restrict__ hsT,
                                              const unsigned* __restrict__ m1slot,
                                              float* __restrict__ SufA,
                                              float* __restrict__ PreB) {
  int t = threadIdx.x;
  int c = blockIdx.x % 65;
  int br = blockIdx.x / 65;  // 0 = A (suffix, e^{s1-M1}), 1 = B (prefix, e^{0.01 s1})
  float M1 = dec(*m1slot);
  const float* hc = hsT + (size_t)c * NROW;
  int qb = t * 16;
  int base = br ? qb : (NROW - 16 - qb);   // 16-aligned float4 window
  float sarr[16], harr[16];
#pragma unroll
  for (int m = 0; m < 4; ++m) {
    float4 v = *(const float4*)&s1s[base + m * 4];
    sarr[m * 4] = v.x; sarr[m * 4 + 1] = v.y; sarr[m * 4 + 2] = v.z; sarr[m * 4 + 3] = v.w;
  }
  if (c < 64) {
#pragma unroll
    for (int m = 0; m < 4; ++m) {
      float4 v = *(const float4*)&hc[base + m * 4];
      harr[m * 4] = v.x; harr[m * 4 + 1] = v.y; harr[m * 4 + 2] = v.z; harr[m * 4 + 3] = v.w;
    }
  } else {
#pragma unroll
    for (int m = 0; m < 16; ++m) harr[m] = 1.0f;
  }
  float vals[16];
#pragma unroll
  for (int e = 0; e < 16; ++e) {
    int ridx = br ? e : (15 - e);
    float s = sarr[ridx];
    float w = br ? __expf(0.01f * s) : __expf(s - M1);
    vals[e] = w * harr[ridx];
  }
  float sum = 0.f;
#pragma unroll
  for (int e = 0; e < 16; ++e) sum += vals[e];
  int lane = t & 63, wid = t >> 6;
  float sc = sum;
#pragma unroll
  for (int off = 1; off < 64; off <<= 1) {
    float o = __shfl_up(sc, off);
    if (lane >= off) sc += o;
  }
  __shared__ float wt[8];
  if (lane == 63) wt[wid] = sc;
  __syncthreads();
  float woff = 0.f;
#pragma unroll
  for (int w = 0; w < 8; ++w)
    if (w < wid) woff += wt[w];
  float p = __shfl_up(sc, 1);
  float run = woff + (lane ? p : 0.f);
  if (br) {
#pragma unroll
    for (int e = 0; e < 16; ++e) {
      PreB[(size_t)(qb + e) * LD65 + c] = run;
      run += vals[e];
    }
    if (t == 511) PreB[(size_t)NROW * LD65 + c] = run;  // total
  } else {
#pragma unroll
    for (int e = 0; e < 16; ++e) {
      run += vals[e];
      SufA[(size_t)(NROW - 1 - (qb + e)) * LD65 + c] = run;
    }
    if (t == 0) SufA[(size_t)NROW * LD65 + c] = 0.f;
  }
}

// K5: per-row closed-form softmax combine + residual + W_f/lrelu + W_o.
// 256 blocks x 256 thr; each wave processes 8 rows with Wf row in registers.
__global__ __launch_bounds__(256) void k_final(const float* __restrict__ h,
    const float* __restrict__ s1s, const float* __restrict__ s2,
    const float* __restrict__ SufA, const float* __restrict__ PreB,
    const unsigned* __restrict__ m1slot, const float* __restrict__ Wf,
    const float* __restrict__ bf, const float* __restrict__ Wo,
    const float* __restrict__ bo, float* __restrict__ out) {
  int t = threadIdx.x;
  int lane = t & 63, wid = t >> 6;
  __shared__ float coarse[64];
  if (t < 64) coarse[t] = s1s[t * 128];
  __syncthreads();
  float4 wf[16];
  const float4* wrow = (const float4*)(Wf + (size_t)lane * HD);
#pragma unroll
  for (int q = 0; q < 16; ++q) wf[q] = wrow[q];
  float bfl = bf[lane], wol = Wo[lane], bo0 = bo[0];
  float M1 = dec(*m1slot);
  float myc = coarse[lane];

  for (int rr = 0; rr < 8; ++rr) {
    int i = blockIdx.x * 32 + wid * 8 + rr;
    float s2i = s2[i];
    float th = -s2i;
    float z = s2i + M1;
    float mi = lrelu(z);
    float cA = __expf(z - mi);
    float cB = __expf(0.01f * s2i - mi);
    int n1 = __popcll(__ballot(myc < th));
    int cnt = 0;
    if (n1 > 0) {
      int L = (n1 - 1) * 128;
      float v2 = s1s[L + 1 + 2 * lane];
      int n2 = __popcll(__ballot(v2 < th));
      cnt = L + 2 * n2;
      if (cnt < NROW && s1s[cnt] < th) cnt++;
    }
    const float* ra = SufA + (size_t)cnt * LD65;
    const float* rb = PreB + (size_t)cnt * LD65;
    float vA = ra[lane], vB = rb[lane];
    float zA = ra[64],  zB = rb[64];
    float Z = cA * zA + cB * zB;
    float h2 = (cA * vA + cB * vB) / Z + h[(size_t)i * HD + lane];
    float acc = bfl;
#pragma unroll
    for (int q = 0; q < 16; ++q) {
      float4 wv = wf[q];
      int c = q * 4;
      acc += wv.x * __shfl(h2, c) + wv.y * __shfl(h2, c + 1) +
             wv.z * __shfl(h2, c + 2) + wv.w * __shfl(h2, c + 3);
    }
    float h3 = lrelu(acc);
    float pv = h3 * wol;
#pragma unroll
    for (int off = 32; off > 0; off >>= 1) pv += __shfl_xor(pv, off);
    if (lane == 0) out[i] = pv + bo0;
  }
}

extern "C" void kernel_launch(void* const* d_in, const int* in_sizes, int n_in,
                              void* d_out, int out_size, void* d_ws, size_t ws_size,
                              hipStream_t stream) {
  const float* x   = (const float*)d_in[0];
  const float* Wfc = (const float*)d_in[1];
  const float* bfc = (const float*)d_in[2];
  const float* Wtr = (const float*)d_in[3];
  const float* btr = (const float*)d_in[4];
  const float* a   = (const float*)d_in[5];
  const float* Wf  = (const float*)d_in[6];
  const float* bf  = (const float*)d_in[7];
  const float* Wo  = (const float*)d_in[8];
  const float* bo  = (const float*)d_in[9];
  float* out = (float*)d_out;

  char* w = (char*)d_ws;
  size_t off = 0;
  auto alloc = [&](size_t bytes) -> void* {
    void* p = w + off;
    off = (off + bytes + 255) & ~(size_t)255;
    return p;
  };
  float* h      = (float*)alloc((size_t)NROW * HD * 4);
  float* s1     = (float*)alloc(NROW * 4);
  float* s2     = (float*)alloc(NROW * 4);
  float* u12    = (float*)alloc(130 * 4);
  unsigned* m1  = (unsigned*)alloc(4);
  int* inv      = (int*)alloc(NROW * 4);
  float* s1s    = (float*)alloc(NROW * 4);
  unsigned short* WhS = (unsigned short*)alloc((size_t)4 * NCH * 64 * 8 * 2);
  unsigned short* WlS = (unsigned short*)alloc((size_t)4 * NCH * 64 * 8 * 2);
  float* hsT    = (float*)alloc((size_t)HD * NROW * 4);
  float* SufA   = (float*)alloc((size_t)(NROW + 1) * LD65 * 4);
  float* PreB   = (float*)alloc((size_t)(NROW + 1) * LD65 * 4);
  (void)in_sizes; (void)n_in; (void)out_size; (void)ws_size;

  k_prep<<<1 + (4 * NCH * 64) / 256, 256, 0, stream>>>(Wtr, btr, a, Wfc, u12, m1, WhS, WlS);
  k_gemm<<<NROW / 16, 256, 0, stream>>>(x, WhS, WlS, bfc, u12, h, s1, s2, m1);
  k_sort<<<NROW / 32, 512, 0, stream>>>(s1, s1s, inv);
  k_trans<<<NROW / 64, 256, 0, stream>>>(h, inv, hsT);
  k_scan<<<130, 512, 0, stream>>>(s1s, hsT, m1, SufA, PreB);
  k_final<<<NROW / 32, 256, 0, stream>>>(h, s1s, s2, SufA, PreB, m1, Wf, bf, Wo, bo, out);
}

// Round 12
// 80.171 us; speedup vs baseline: 1.5157x; 1.1536x over previous
//
#include <hip/hip_runtime.h>

#define NROW 8192
#define DIM  1447
#define HD   64
#define NCH  48        // W swizzle stride: 48 k-chunks of 32 (zero-padded)
#define KH   736       // K-half = 23 steps of 32
#define LD65 65        // scan row layout [q][65]

typedef __attribute__((ext_vector_type(8))) short bf16x8;
typedef __attribute__((ext_vector_type(4))) float f32x4;
typedef float f32x4u __attribute__((ext_vector_type(4), aligned(4)));  // 4B-aligned 16B load

__device__ __forceinline__ float lrelu(float v) { return v >= 0.f ? v : 0.01f * v; }

__device__ __forceinline__ unsigned short f2bf(float f) {
  unsigned u = __float_as_uint(f);
  u = u + 0x7fffu + ((u >> 16) & 1u);   // RNE
  return (unsigned short)(u >> 16);
}
__device__ __forceinline__ float bf2f(unsigned short s) {
  return __uint_as_float((unsigned)s << 16);
}

// monotone float<->uint encoding (order-preserving) for atomicMax / sort keys
__device__ __forceinline__ unsigned enc(float f) {
  unsigned u = __float_as_uint(f);
  return (u & 0x80000000u) ? ~u : (u | 0x80000000u);
}
__device__ __forceinline__ float dec(unsigned k) {
  unsigned u = (k & 0x80000000u) ? (k & 0x7fffffffu) : ~k;
  return __uint_as_float(u);
}

union BU { int4 i; bf16x8 v; };

// K0: block 0: u1/u2/c1/c2 prep + init M1.
// blocks 1..48: W_fc -> bf16 hi/lo in MFMA-fragment-swizzled order:
//   flat[((cg*48 + s)*64 + lane)*8 + e], col = cg*16 + (lane&15),
//   k = s*32 + (lane>>4)*8 + e   (zero-padded past DIM)
__global__ void k_prep(const float* __restrict__ Wtr, const float* __restrict__ btr,
                       const float* __restrict__ a, const float* __restrict__ Wfc,
                       float* __restrict__ u12, unsigned* __restrict__ m1slot,
                       unsigned short* __restrict__ WhS, unsigned short* __restrict__ WlS) {
  int t = threadIdx.x;
  int b = blockIdx.x;
  if (b == 0) {
    if (t < 64) {
      float u1 = 0.f, u2 = 0.f;
      for (int o = 0; o < 64; ++o) {
        float w = Wtr[o * 64 + t];
        u1 += w * a[o];
        u2 += w * a[64 + o];
      }
      u12[t] = u1; u12[64 + t] = u2;
      if (t == 0) {
        float c1 = 0.f, c2 = 0.f;
        for (int o = 0; o < 64; ++o) { c1 += btr[o] * a[o]; c2 += btr[o] * a[64 + o]; }
        u12[128] = c1; u12[129] = c2;
        *m1slot = 0u;
      }
    }
  } else {
    int wi = (b - 1) * 256 + t;           // < 4*48*64 = 12288
    int cg = wi / (NCH * 64);
    int rem = wi - cg * (NCH * 64);
    int s = rem >> 6;
    int l = rem & 63;
    int col = cg * 16 + (l & 15);
    int k0 = s * 32 + (l >> 4) * 8;
    unsigned short hv[8], lv[8];
#pragma unroll
    for (int e = 0; e < 8; ++e) {
      int k = k0 + e;
      float v = (k < DIM) ? Wfc[(size_t)col * DIM + k] : 0.f;
      unsigned short hi = f2bf(v);
      hv[e] = hi;
      lv[e] = f2bf(v - bf2f(hi));
    }
    size_t base = (size_t)wi * 8;
#pragma unroll
    for (int e = 0; e < 8; ++e) { WhS[base + e] = hv[e]; WlS[base + e] = lv[e]; }
  }
}

// K1: partial GEMM, split-bf16 MFMA, LDS-staged + K-split for occupancy.
// 1024 blocks (512 rowblocks x 2 K-halves) x 256 thr (4 colgroup waves)
// -> 4 blocks/CU, 16 waves/CU. Per block: 16-row tile, 6 chunks of 128k,
// x staged 16B/lane coalesced -> converted once -> bf16 hi/lo LDS
// (136-short rows: 2-way bank aliasing = free); B 1KB-contiguous from
// pre-swizzled W; 1 barrier/chunk; f32 partials out.
__global__ __launch_bounds__(256, 4) void k_gemm(const float* __restrict__ x,
    const unsigned short* __restrict__ WhS, const unsigned short* __restrict__ WlS,
    float* __restrict__ part) {
  __shared__ unsigned short XH[2][16][136], XL[2][16][136];  // 17.4 KB
  int t = threadIdx.x;
  int cg = t >> 6;           // colgroup 0..3
  int l = t & 63;
  int l15 = l & 15, l4 = l >> 4;
  int rb = blockIdx.x >> 1;
  int kq = blockIdx.x & 1;   // K-half
  int R0 = rb * 16;
  int srow = t >> 4;         // staging row 0..15
  int scb = (t & 15) * 8;    // staging col octet 0..120

  const float* xst = x + (size_t)(R0 + srow) * DIM;
  const unsigned short* whp = WhS + (((size_t)cg * NCH) << 9) + (l << 3);
  const unsigned short* wlp = WlS + (((size_t)cg * NCH) << 9) + (l << 3);

  float xr[8];

#define STLOAD(C)                                                          \
  do {                                                                     \
    int kg_ = kq * KH + (C) * 128 + scb;                                   \
    if (kq == 0 || (C) < 5) {                                              \
      f32x4u a0_ = *(const f32x4u*)(xst + kg_);                            \
      f32x4u a1_ = *(const f32x4u*)(xst + kg_ + 4);                        \
      xr[0] = a0_[0]; xr[1] = a0_[1]; xr[2] = a0_[2]; xr[3] = a0_[3];      \
      xr[4] = a1_[0]; xr[5] = a1_[1]; xr[6] = a1_[2]; xr[7] = a1_[3];      \
    } else {                                                               \
      _Pragma("unroll")                                                    \
      for (int e = 0; e < 8; ++e) xr[e] = (kg_ + e < DIM) ? xst[kg_ + e] : 0.f; \
    }                                                                      \
  } while (0)

#define STWRITE(B)                                                         \
  do {                                                                     \
    unsigned hw_[4], lw_[4];                                               \
    _Pragma("unroll")                                                      \
    for (int q_ = 0; q_ < 4; ++q_) {                                       \
      unsigned short h0_ = f2bf(xr[2 * q_]), h1_ = f2bf(xr[2 * q_ + 1]);   \
      unsigned short l0_ = f2bf(xr[2 * q_] - bf2f(h0_));                   \
      unsigned short l1_ = f2bf(xr[2 * q_ + 1] - bf2f(h1_));               \
      hw_[q_] = (unsigned)h0_ | ((unsigned)h1_ << 16);                     \
      lw_[q_] = (unsigned)l0_ | ((unsigned)l1_ << 16);                     \
    }                                                                      \
    *(int4*)&XH[B][srow][scb] = make_int4(hw_[0], hw_[1], hw_[2], hw_[3]); \
    *(int4*)&XL[B][srow][scb] = make_int4(lw_[0], lw_[1], lw_[2], lw_[3]); \
  } while (0)

  f32x4 acc = {0.f, 0.f, 0.f, 0.f};

  STLOAD(0);
  STWRITE(0);
  __syncthreads();

  for (int c = 0; c < 6; ++c) {
    int buf = c & 1;
    if (c < 5) STLOAD(c + 1);
    int nst = (c == 5) ? 3 : 4;
    for (int sl = 0; sl < nst; ++sl) {
      int sg = kq * 23 + c * 4 + sl;        // global k-step < 46
      BU bh, bl;
      bh.i = *(const int4*)(whp + ((size_t)sg << 9));
      bl.i = *(const int4*)(wlp + ((size_t)sg << 9));
      bf16x8 ah = *(const bf16x8*)&XH[buf][l15][sl * 32 + l4 * 8];
      bf16x8 al = *(const bf16x8*)&XL[buf][l15][sl * 32 + l4 * 8];
      acc = __builtin_amdgcn_mfma_f32_16x16x32_bf16(ah, bh.v, acc, 0, 0, 0);
      acc = __builtin_amdgcn_mfma_f32_16x16x32_bf16(ah, bl.v, acc, 0, 0, 0);
      acc = __builtin_amdgcn_mfma_f32_16x16x32_bf16(al, bh.v, acc, 0, 0, 0);
    }
    if (c < 5) STWRITE(buf ^ 1);
    __syncthreads();
  }
#undef STLOAD
#undef STWRITE

  // D layout: col = lane&15, row = (lane>>4)*4 + reg  [m89-verified]
  float* pq = part + (size_t)kq * (NROW * HD);
  int col = cg * 16 + l15;
#pragma unroll
  for (int r = 0; r < 4; ++r) {
    int row = R0 + l4 * 4 + r;
    pq[(size_t)row * HD + col] = acc[r];
  }
}

// K1b: h = lrelu(sum_q part[q] + b_fc); fused s1/s2 dots + global max(s1).
// 256 blocks x 256 thr; 32 rows/block; 8 threads/row (8 cols each).
__global__ __launch_bounds__(256) void k_hred(const float* __restrict__ part,
    const float* __restrict__ bfc, const float* __restrict__ u12,
    float* __restrict__ h, float* __restrict__ s1, float* __restrict__ s2,
    unsigned* __restrict__ m1slot) {
  int t = threadIdx.x;
  int r = blockIdx.x * 32 + (t >> 3);
  int cg = t & 7;
  size_t base = (size_t)r * HD + cg * 8;
  float v[8];
  {
    const float4* p0 = (const float4*)&part[base];
    const float4* p1 = (const float4*)&part[(size_t)(NROW * HD) + base];
    float4 a0 = p0[0], a1 = p0[1], b0 = p1[0], b1 = p1[1];
    v[0] = a0.x + b0.x; v[1] = a0.y + b0.y; v[2] = a0.z + b0.z; v[3] = a0.w + b0.w;
    v[4] = a1.x + b1.x; v[5] = a1.y + b1.y; v[6] = a1.z + b1.z; v[7] = a1.w + b1.w;
  }
  float d1 = 0.f, d2 = 0.f;
#pragma unroll
  for (int j = 0; j < 8; ++j) {
    int c = cg * 8 + j;
    float hv = lrelu(v[j] + bfc[c]);
    v[j] = hv;
    d1 += hv * u12[c];
    d2 += hv * u12[64 + c];
  }
  float4* hw = (float4*)&h[base];
  hw[0] = make_float4(v[0], v[1], v[2], v[3]);
  hw[1] = make_float4(v[4], v[5], v[6], v[7]);
#pragma unroll
  for (int off = 1; off < 8; off <<= 1) {
    d1 += __shfl_xor(d1, off);
    d2 += __shfl_xor(d2, off);
  }
  float sv1 = d1 + u12[128];
  float sv2 = d2 + u12[129];
  if (cg == 0) { s1[r] = sv1; s2[r] = sv2; }
  float m = sv1;
#pragma unroll
  for (int off = 8; off < 64; off <<= 1) m = fmaxf(m, __shfl_xor(m, off));
  if ((t & 63) == 0) atomicMax(m1slot, enc(m));
}

// K2: exact-rank sort via unique u64 keys (enc(s1)<<13 | j): no ties possible,
// 2-op compares. 256 blocks x 512 thr; block owns 32 j's, 4 j's per thread
// (register-tiled), 64 scan-groups of 128 elements; LDS-atomic combine.
__global__ __launch_bounds__(512) void k_sort(const float* __restrict__ s1,
                                              float* __restrict__ s1s,
                                              int* __restrict__ inv) {
  __shared__ unsigned long long keys[NROW];  // 64 KB
  __shared__ int lcnt[32];
  int t = threadIdx.x;
#pragma unroll
  for (int i = 0; i < 16; ++i) {
    int j = i * 512 + t;
    keys[j] = ((unsigned long long)enc(s1[j]) << 13) | (unsigned)j;
  }
  if (t < 32) lcnt[t] = 0;
  __syncthreads();
  int jb = blockIdx.x * 32 + (t & 7) * 4;
  unsigned long long k0 = keys[jb], k1 = keys[jb + 1], k2 = keys[jb + 2], k3 = keys[jb + 3];
  int g = t >> 3;  // 0..63, window [g*128, g*128+128)
  int c0 = 0, c1 = 0, c2 = 0, c3 = 0;
#pragma unroll 8
  for (int e = 0; e < 128; ++e) {
    unsigned long long v = keys[g * 128 + ((e + g) & 127)];  // phased: conflict-free
    c0 += (v < k0); c1 += (v < k1); c2 += (v < k2); c3 += (v < k3);
  }
  int js = (t & 7) * 4;
  atomicAdd(&lcnt[js], c0);
  atomicAdd(&lcnt[js + 1], c1);
  atomicAdd(&lcnt[js + 2], c2);
  atomicAdd(&lcnt[js + 3], c3);
  __syncthreads();
  if (t < 32) {
    int r = lcnt[t];
    int j = blockIdx.x * 32 + t;
    inv[r] = j;
    s1s[r] = s1[j];
  }
}

// K3: hsT[c][r] = h[inv[r]][c]  (coalesced gather + LDS transpose)
__global__ __launch_bounds__(256) void k_trans(const float* __restrict__ h,
                                               const int* __restrict__ inv,
                                               float* __restrict__ hsT) {
  __shared__ float tile[64][65];
  int t = threadIdx.x;
  int r0 = blockIdx.x * 64;
  int rr = t >> 2;
  int cseg = (t & 3) * 16;
  int j = inv[r0 + rr];
#pragma unroll
  for (int q = 0; q < 4; ++q) {
    float4 v = *(const float4*)&h[(size_t)j * HD + cseg + q * 4];
    tile[rr][cseg + q * 4]     = v.x;
    tile[rr][cseg + q * 4 + 1] = v.y;
    tile[rr][cseg + q * 4 + 2] = v.z;
    tile[rr][cseg + q * 4 + 3] = v.w;
  }
  __syncthreads();
  int c = t >> 2;
  int rseg = (t & 3) * 16;
#pragma unroll
  for (int e = 0; e < 16; e += 4) {
    int r = rseg + e;
    float4 v = make_float4(tile[r][c], tile[r + 1][c], tile[r + 2][c], tile[r + 3][c]);
    *(float4*)&hsT[(size_t)c * NROW + r0 + r] = v;
  }
}

// K4: per-column prefix(B)/suffix(A) scans over sorted order (float4-streamed),
// output layout [q][65] for coalesced k_final reads.
__global__ __launch_bounds__(512) void k_scan(const float* __restrict__ s1s,
                                              const float* __restrict__ hsT,
                                              const unsigned* __restrict__ m1slot,
                                              float* __restrict__ SufA,
                                              float* __restrict__ PreB) {
  int t = threadIdx.x;
  int c = blockIdx.x % 65;
  int br = blockIdx.x / 65;  // 0 = A (suffix, e^{s1-M1}), 1 = B (prefix, e^{0.01 s1})
  float M1 = dec(*m1slot);
  const float* hc = hsT + (size_t)c * NROW;
  int qb = t * 16;
  int base = br ? qb : (NROW - 16 - qb);   // 16-aligned float4 window
  float sarr[16], harr[16];
#pragma unroll
  for (int m = 0; m < 4; ++m) {
    float4 v = *(const float4*)&s1s[base + m * 4];
    sarr[m * 4] = v.x; sarr[m * 4 + 1] = v.y; sarr[m * 4 + 2] = v.z; sarr[m * 4 + 3] = v.w;
  }
  if (c < 64) {
#pragma unroll
    for (int m = 0; m < 4; ++m) {
      float4 v = *(const float4*)&hc[base + m * 4];
      harr[m * 4] = v.x; harr[m * 4 + 1] = v.y; harr[m * 4 + 2] = v.z; harr[m * 4 + 3] = v.w;
    }
  } else {
#pragma unroll
    for (int m = 0; m < 16; ++m) harr[m] = 1.0f;
  }
  float vals[16];
#pragma unroll
  for (int e = 0; e < 16; ++e) {
    int ridx = br ? e : (15 - e);
    float s = sarr[ridx];
    float w = br ? __expf(0.01f * s) : __expf(s - M1);
    vals[e] = w * harr[ridx];
  }
  float sum = 0.f;
#pragma unroll
  for (int e = 0; e < 16; ++e) sum += vals[e];
  int lane = t & 63, wid = t >> 6;
  float sc = sum;
#pragma unroll
  for (int off = 1; off < 64; off <<= 1) {
    float o = __shfl_up(sc, off);
    if (lane >= off) sc += o;
  }
  __shared__ float wt[8];
  if (lane == 63) wt[wid] = sc;
  __syncthreads();
  float woff = 0.f;
#pragma unroll
  for (int w = 0; w < 8; ++w)
    if (w < wid) woff += wt[w];
  float p = __shfl_up(sc, 1);
  float run = woff + (lane ? p : 0.f);
  if (br) {
#pragma unroll
    for (int e = 0; e < 16; ++e) {
      PreB[(size_t)(qb + e) * LD65 + c] = run;
      run += vals[e];
    }
    if (t == 511) PreB[(size_t)NROW * LD65 + c] = run;  // total
  } else {
#pragma unroll
    for (int e = 0; e < 16; ++e) {
      run += vals[e];
      SufA[(size_t)(NROW - 1 - (qb + e)) * LD65 + c] = run;
    }
    if (t == 0) SufA[(size_t)NROW * LD65 + c] = 0.f;
  }
}

// K5: per-row closed-form softmax combine + residual + W_f/lrelu + W_o.
// 256 blocks x 256 thr; each wave processes 8 rows with Wf row in registers.
__global__ __launch_bounds__(256) void k_final(const float* __restrict__ h,
    const float* __restrict__ s1s, const float* __restrict__ s2,
    const float* __restrict__ SufA, const float* __restrict__ PreB,
    const unsigned* __restrict__ m1slot, const float* __restrict__ Wf,
    const float* __restrict__ bf, const float* __restrict__ Wo,
    const float* __restrict__ bo, float* __restrict__ out) {
  int t = threadIdx.x;
  int lane = t & 63, wid = t >> 6;
  __shared__ float coarse[64];
  if (t < 64) coarse[t] = s1s[t * 128];
  __syncthreads();
  float4 wf[16];
  const float4* wrow = (const float4*)(Wf + (size_t)lane * HD);
#pragma unroll
  for (int q = 0; q < 16; ++q) wf[q] = wrow[q];
  float bfl = bf[lane], wol = Wo[lane], bo0 = bo[0];
  float M1 = dec(*m1slot);
  float myc = coarse[lane];

  for (int rr = 0; rr < 8; ++rr) {
    int i = blockIdx.x * 32 + wid * 8 + rr;
    float s2i = s2[i];
    float th = -s2i;
    float z = s2i + M1;
    float mi = lrelu(z);
    float cA = __expf(z - mi);
    float cB = __expf(0.01f * s2i - mi);
    int n1 = __popcll(__ballot(myc < th));
    int cnt = 0;
    if (n1 > 0) {
      int L = (n1 - 1) * 128;
      float v2 = s1s[L + 1 + 2 * lane];
      int n2 = __popcll(__ballot(v2 < th));
      cnt = L + 2 * n2;
      if (cnt < NROW && s1s[cnt] < th) cnt++;
    }
    const float* ra = SufA + (size_t)cnt * LD65;
    const float* rb = PreB + (size_t)cnt * LD65;
    float vA = ra[lane], vB = rb[lane];
    float zA = ra[64],  zB = rb[64];
    float Z = cA * zA + cB * zB;
    float h2 = (cA * vA + cB * vB) / Z + h[(size_t)i * HD + lane];
    float acc = bfl;
#pragma unroll
    for (int q = 0; q < 16; ++q) {
      float4 wv = wf[q];
      int c = q * 4;
      acc += wv.x * __shfl(h2, c) + wv.y * __shfl(h2, c + 1) +
             wv.z * __shfl(h2, c + 2) + wv.w * __shfl(h2, c + 3);
    }
    float h3 = lrelu(acc);
    float pv = h3 * wol;
#pragma unroll
    for (int off = 32; off > 0; off >>= 1) pv += __shfl_xor(pv, off);
    if (lane == 0) out[i] = pv + bo0;
  }
}

extern "C" void kernel_launch(void* const* d_in, const int* in_sizes, int n_in,
                              void* d_out, int out_size, void* d_ws, size_t ws_size,
                              hipStream_t stream) {
  const float* x   = (const float*)d_in[0];
  const float* Wfc = (const float*)d_in[1];
  const float* bfc = (const float*)d_in[2];
  const float* Wtr = (const float*)d_in[3];
  const float* btr = (const float*)d_in[4];
  const float* a   = (const float*)d_in[5];
  const float* Wf  = (const float*)d_in[6];
  const float* bf  = (const float*)d_in[7];
  const float* Wo  = (const float*)d_in[8];
  const float* bo  = (const float*)d_in[9];
  float* out = (float*)d_out;

  char* w = (char*)d_ws;
  size_t off = 0;
  auto alloc = [&](size_t bytes) -> void* {
    void* p = w + off;
    off = (off + bytes + 255) & ~(size_t)255;
    return p;
  };
  float* h      = (float*)alloc((size_t)NROW * HD * 4);
  float* s1     = (float*)alloc(NROW * 4);
  float* s2     = (float*)alloc(NROW * 4);
  float* u12    = (float*)alloc(130 * 4);
  unsigned* m1  = (unsigned*)alloc(4);
  int* inv      = (int*)alloc(NROW * 4);
  float* s1s    = (float*)alloc(NROW * 4);
  unsigned short* WhS = (unsigned short*)alloc((size_t)4 * NCH * 64 * 8 * 2);
  unsigned short* WlS = (unsigned short*)alloc((size_t)4 * NCH * 64 * 8 * 2);
  float* part   = (float*)alloc((size_t)2 * NROW * HD * 4);   // 4 MB f32 partials
  float* hsT    = (float*)alloc((size_t)HD * NROW * 4);
  float* SufA   = (float*)alloc((size_t)(NROW + 1) * LD65 * 4);
  float* PreB   = (float*)alloc((size_t)(NROW + 1) * LD65 * 4);
  (void)in_sizes; (void)n_in; (void)out_size; (void)ws_size;

  k_prep<<<1 + (4 * NCH * 64) / 256, 256, 0, stream>>>(Wtr, btr, a, Wfc, u12, m1, WhS, WlS);
  k_gemm<<<(NROW / 16) * 2, 256, 0, stream>>>(x, WhS, WlS, part);
  k_hred<<<NROW / 32, 256, 0, stream>>>(part, bfc, u12, h, s1, s2, m1);
  k_sort<<<NROW / 32, 512, 0, stream>>>(s1, s1s, inv);
  k_trans<<<NROW / 64, 256, 0, stream>>>(h, inv, hsT);
  k_scan<<<130, 512, 0, stream>>>(s1s, hsT, m1, SufA, PreB);
  k_final<<<NROW / 32, 256, 0, stream>>>(h, s1s, s2, SufA, PreB, m1, Wf, bf, Wo, bo, out);
}

// Round 13
// 71.586 us; speedup vs baseline: 1.6974x; 1.1199x over previous
//
#include <hip/hip_runtime.h>

#define NROW 8192
#define DIM  1447
#define HD   64
#define NCH  48        // W swizzle stride: 48 k-chunks of 32 (zero-padded)
#define LD65 65        // scan row layout [q][65]
#define XLD  264       // LDS row stride (shorts): 16B-aligned, 2-way banks (free)

typedef __attribute__((ext_vector_type(8))) short bf16x8;
typedef __attribute__((ext_vector_type(4))) float f32x4;
typedef float f32x4u __attribute__((ext_vector_type(4), aligned(4)));  // 4B-aligned 16B load

__device__ __forceinline__ float lrelu(float v) { return v >= 0.f ? v : 0.01f * v; }

__device__ __forceinline__ unsigned short f2bf(float f) {
  unsigned u = __float_as_uint(f);
  u = u + 0x7fffu + ((u >> 16) & 1u);   // RNE
  return (unsigned short)(u >> 16);
}
__device__ __forceinline__ float bf2f(unsigned short s) {
  return __uint_as_float((unsigned)s << 16);
}

// monotone float<->uint encoding (order-preserving) for atomicMax / sort keys
__device__ __forceinline__ unsigned enc(float f) {
  unsigned u = __float_as_uint(f);
  return (u & 0x80000000u) ? ~u : (u | 0x80000000u);
}
__device__ __forceinline__ float dec(unsigned k) {
  unsigned u = (k & 0x80000000u) ? (k & 0x7fffffffu) : ~k;
  return __uint_as_float(u);
}

union BU { int4 i; bf16x8 v; };

// K0: block 0: u1/u2/c1/c2 prep + init M1.
// blocks 1..48: W_fc -> bf16 hi/lo in MFMA-fragment-swizzled order:
//   flat[((cg*48 + s)*64 + lane)*8 + e], col = cg*16 + (lane&15),
//   k = s*32 + (lane>>4)*8 + e   (zero-padded past DIM)
__global__ void k_prep(const float* __restrict__ Wtr, const float* __restrict__ btr,
                       const float* __restrict__ a, const float* __restrict__ Wfc,
                       float* __restrict__ u12, unsigned* __restrict__ m1slot,
                       unsigned short* __restrict__ WhS, unsigned short* __restrict__ WlS) {
  int t = threadIdx.x;
  int b = blockIdx.x;
  if (b == 0) {
    if (t < 64) {
      float u1 = 0.f, u2 = 0.f;
      for (int o = 0; o < 64; ++o) {
        float w = Wtr[o * 64 + t];
        u1 += w * a[o];
        u2 += w * a[64 + o];
      }
      u12[t] = u1; u12[64 + t] = u2;
      if (t == 0) {
        float c1 = 0.f, c2 = 0.f;
        for (int o = 0; o < 64; ++o) { c1 += btr[o] * a[o]; c2 += btr[o] * a[64 + o]; }
        u12[128] = c1; u12[129] = c2;
        *m1slot = 0u;
      }
    }
  } else {
    int wi = (b - 1) * 256 + t;           // < 4*48*64 = 12288
    int cg = wi / (NCH * 64);
    int rem = wi - cg * (NCH * 64);
    int s = rem >> 6;
    int l = rem & 63;
    int col = cg * 16 + (l & 15);
    int k0 = s * 32 + (l >> 4) * 8;
    unsigned short hv[8], lv[8];
#pragma unroll
    for (int e = 0; e < 8; ++e) {
      int k = k0 + e;
      float v = (k < DIM) ? Wfc[(size_t)col * DIM + k] : 0.f;
      unsigned short hi = f2bf(v);
      hv[e] = hi;
      lv[e] = f2bf(v - bf2f(hi));
    }
    size_t base = (size_t)wi * 8;
#pragma unroll
    for (int e = 0; e < 8; ++e) { WhS[base + e] = hv[e]; WlS[base + e] = lv[e]; }
  }
}

// K1: h = lrelu(x @ W_fc.T + b_fc), split-bf16 MFMA, fused s1/s2/max epilogue.
// 512 blocks x 512 thr (8 waves = 4 colgroups x 2 K-halves) -> 2 blocks/CU,
// 16 waves/CU. Per chunk: 16 rows x 256k staged (128k per K-half) with
// coalesced f32x4 loads, converted ONCE to bf16 hi/lo in LDS (row stride 264
// shorts: 16B-aligned, 2-way banks = free). B 1KB-contiguous from pre-swizzled
// W. 6 chunks double-buffered, fully unrolled, 1 barrier/chunk. K-half
// partials combined via Pacc (R6 epilogue).
__global__ __launch_bounds__(512, 4) void k_gemm(const float* __restrict__ x,
    const unsigned short* __restrict__ WhS, const unsigned short* __restrict__ WlS,
    const float* __restrict__ bfc, const float* __restrict__ u12,
    float* __restrict__ h, float* __restrict__ s1, float* __restrict__ s2,
    unsigned* __restrict__ m1slot) {
  __shared__ unsigned short XH[2][16][XLD], XL[2][16][XLD];  // 33 KB
  __shared__ float Pacc[4][16][17];
  __shared__ float Pd1[16][4], Pd2[16][4];
  int t = threadIdx.x;
  int wv = t >> 6;
  int l = t & 63;
  int l15 = l & 15, l4 = l >> 4;
  int cg = wv & 3;           // colgroup 0..3
  int kh = wv >> 2;          // K-half 0/1 (23 steps each)
  int R0 = blockIdx.x * 16;
  int srow = t >> 5;         // staging row 0..15
  int scol = (t & 31) * 8;   // staging col 0..248 (LDS shorts / k within chunk-pair)

  const float* xst = x + (size_t)(R0 + srow) * DIM;
  const unsigned short* whp = WhS + (((size_t)cg * NCH) << 9) + (l << 3);
  const unsigned short* wlp = WlS + (((size_t)cg * NCH) << 9) + (l << 3);

  float xr[8];
  // global k for staging: cols [0,128) = K-half 0 chunk (k = c*128 + scol),
  // cols [128,256) = K-half 1 chunk (k = 736 + c*128 + scol-128)
  int kadd = (scol < 128) ? scol : (608 + scol);

#define STLOAD(C)                                                          \
  do {                                                                     \
    int kg_ = (C) * 128 + kadd;                                            \
    if ((C) == 5 && scol >= 128) {  /* tail: k in [1376,1504) -> mask */   \
      _Pragma("unroll")                                                    \
      for (int e = 0; e < 8; ++e) xr[e] = (kg_ + e < DIM) ? xst[kg_ + e] : 0.f; \
    } else {                                                               \
      f32x4u a0_ = *(const f32x4u*)(xst + kg_);                            \
      f32x4u a1_ = *(const f32x4u*)(xst + kg_ + 4);                        \
      xr[0] = a0_[0]; xr[1] = a0_[1]; xr[2] = a0_[2]; xr[3] = a0_[3];      \
      xr[4] = a1_[0]; xr[5] = a1_[1]; xr[6] = a1_[2]; xr[7] = a1_[3];      \
    }                                                                      \
  } while (0)

#define STWRITE(B)                                                         \
  do {                                                                     \
    unsigned hw_[4], lw_[4];                                               \
    _Pragma("unroll")                                                      \
    for (int q_ = 0; q_ < 4; ++q_) {                                       \
      unsigned short h0_ = f2bf(xr[2 * q_]), h1_ = f2bf(xr[2 * q_ + 1]);   \
      unsigned short l0_ = f2bf(xr[2 * q_] - bf2f(h0_));                   \
      unsigned short l1_ = f2bf(xr[2 * q_ + 1] - bf2f(h1_));               \
      hw_[q_] = (unsigned)h0_ | ((unsigned)h1_ << 16);                     \
      lw_[q_] = (unsigned)l0_ | ((unsigned)l1_ << 16);                     \
    }                                                                      \
    *(int4*)&XH[B][srow][scol] = make_int4(hw_[0], hw_[1], hw_[2], hw_[3]); \
    *(int4*)&XL[B][srow][scol] = make_int4(lw_[0], lw_[1], lw_[2], lw_[3]); \
  } while (0)

  f32x4 acc = {0.f, 0.f, 0.f, 0.f};

  STLOAD(0);
  STWRITE(0);
  __syncthreads();

#pragma unroll
  for (int c = 0; c < 6; ++c) {
    int buf = c & 1;
    if (c < 5) STLOAD(c + 1);
    int nst = (c == 5) ? 3 : 4;
#pragma unroll
    for (int ii = 0; ii < 4; ++ii) {
      if (ii < nst) {
        int sg = kh * 23 + c * 4 + ii;     // global k-step < 46
        BU bh, bl;
        bh.i = *(const int4*)(whp + ((size_t)sg << 9));
        bl.i = *(const int4*)(wlp + ((size_t)sg << 9));
        bf16x8 ah = *(const bf16x8*)&XH[buf][l15][kh * 128 + ii * 32 + l4 * 8];
        bf16x8 al = *(const bf16x8*)&XL[buf][l15][kh * 128 + ii * 32 + l4 * 8];
        acc = __builtin_amdgcn_mfma_f32_16x16x32_bf16(ah, bh.v, acc, 0, 0, 0);
        acc = __builtin_amdgcn_mfma_f32_16x16x32_bf16(ah, bl.v, acc, 0, 0, 0);
        acc = __builtin_amdgcn_mfma_f32_16x16x32_bf16(al, bh.v, acc, 0, 0, 0);
      }
    }
    if (c < 5) STWRITE(buf ^ 1);
    __syncthreads();
  }
#undef STLOAD
#undef STWRITE

  // epilogue: combine K-halves via Pacc, bias + lrelu + h store, s1/s2 + max.
  // D layout: col = lane&15, row = (lane>>4)*4 + reg  [m89-verified]
  if (kh == 1) {
#pragma unroll
    for (int r = 0; r < 4; ++r) Pacc[cg][l4 * 4 + r][l15] = acc[r];
  }
  __syncthreads();
  if (kh == 0) {
    int col = cg * 16 + l15;
    float bb = bfc[col];
    float u1c = u12[col], u2c = u12[64 + col];
#pragma unroll
    for (int r = 0; r < 4; ++r) {
      int rl = l4 * 4 + r;
      float hv = lrelu(acc[r] + Pacc[cg][rl][l15] + bb);
      h[(size_t)(R0 + rl) * HD + col] = hv;
      float d1 = hv * u1c, d2 = hv * u2c;
      d1 += __shfl_xor(d1, 1); d1 += __shfl_xor(d1, 2);
      d1 += __shfl_xor(d1, 4); d1 += __shfl_xor(d1, 8);
      d2 += __shfl_xor(d2, 1); d2 += __shfl_xor(d2, 2);
      d2 += __shfl_xor(d2, 4); d2 += __shfl_xor(d2, 8);
      if (l15 == 0) { Pd1[rl][cg] = d1; Pd2[rl][cg] = d2; }
    }
  }
  __syncthreads();
  if (t < 16) {
    float d1 = Pd1[t][0] + Pd1[t][1] + Pd1[t][2] + Pd1[t][3] + u12[128];
    float d2 = Pd2[t][0] + Pd2[t][1] + Pd2[t][2] + Pd2[t][3] + u12[129];
    int gr = R0 + t;
    s1[gr] = d1;
    s2[gr] = d2;
    float m = d1;
    m = fmaxf(m, __shfl_xor(m, 1));
    m = fmaxf(m, __shfl_xor(m, 2));
    m = fmaxf(m, __shfl_xor(m, 4));
    m = fmaxf(m, __shfl_xor(m, 8));
    if (t == 0) atomicMax(m1slot, enc(m));
  }
}

// K2: exact-rank sort via unique u64 keys (enc(s1)<<13 | j): no ties possible,
// 2-op compares. 256 blocks x 512 thr; block owns 32 j's, 4 j's per thread
// (register-tiled), 64 scan-groups of 128 elements; LDS-atomic combine.
__global__ __launch_bounds__(512) void k_sort(const float* __restrict__ s1,
                                              float* __restrict__ s1s,
                                              int* __restrict__ inv) {
  __shared__ unsigned long long keys[NROW];  // 64 KB
  __shared__ int lcnt[32];
  int t = threadIdx.x;
#pragma unroll
  for (int i = 0; i < 16; ++i) {
    int j = i * 512 + t;
    keys[j] = ((unsigned long long)enc(s1[j]) << 13) | (unsigned)j;
  }
  if (t < 32) lcnt[t] = 0;
  __syncthreads();
  int jb = blockIdx.x * 32 + (t & 7) * 4;
  unsigned long long k0 = keys[jb], k1 = keys[jb + 1], k2 = keys[jb + 2], k3 = keys[jb + 3];
  int g = t >> 3;  // 0..63, window [g*128, g*128+128)
  int c0 = 0, c1 = 0, c2 = 0, c3 = 0;
#pragma unroll 8
  for (int e = 0; e < 128; ++e) {
    unsigned long long v = keys[g * 128 + ((e + g) & 127)];  // phased: conflict-free
    c0 += (v < k0); c1 += (v < k1); c2 += (v < k2); c3 += (v < k3);
  }
  int js = (t & 7) * 4;
  atomicAdd(&lcnt[js], c0);
  atomicAdd(&lcnt[js + 1], c1);
  atomicAdd(&lcnt[js + 2], c2);
  atomicAdd(&lcnt[js + 3], c3);
  __syncthreads();
  if (t < 32) {
    int r = lcnt[t];
    int j = blockIdx.x * 32 + t;
    inv[r] = j;
    s1s[r] = s1[j];
  }
}

// K3: hsT[c][r] = h[inv[r]][c]  (coalesced gather + LDS transpose)
__global__ __launch_bounds__(256) void k_trans(const float* __restrict__ h,
                                               const int* __restrict__ inv,
                                               float* __restrict__ hsT) {
  __shared__ float tile[64][65];
  int t = threadIdx.x;
  int r0 = blockIdx.x * 64;
  int rr = t >> 2;
  int cseg = (t & 3) * 16;
  int j = inv[r0 + rr];
#pragma unroll
  for (int q = 0; q < 4; ++q) {
    float4 v = *(const float4*)&h[(size_t)j * HD + cseg + q * 4];
    tile[rr][cseg + q * 4]     = v.x;
    tile[rr][cseg + q * 4 + 1] = v.y;
    tile[rr][cseg + q * 4 + 2] = v.z;
    tile[rr][cseg + q * 4 + 3] = v.w;
  }
  __syncthreads();
  int c = t >> 2;
  int rseg = (t & 3) * 16;
#pragma unroll
  for (int e = 0; e < 16; e += 4) {
    int r = rseg + e;
    float4 v = make_float4(tile[r][c], tile[r + 1][c], tile[r + 2][c], tile[r + 3][c]);
    *(float4*)&hsT[(size_t)c * NROW + r0 + r] = v;
  }
}

// K4: per-column prefix(B)/suffix(A) scans over sorted order (float4-streamed),
// output layout [q][65] for coalesced k_final reads.
__global__ __launch_bounds__(512) void k_scan(const float* __restrict__ s1s,
                                              const float* __restrict__ hsT,
                                              const unsigned* __restrict__ m1slot,
                                              float* __restrict__ SufA,
                                              float* __restrict__ PreB) {
  int t = threadIdx.x;
  int c = blockIdx.x % 65;
  int br = blockIdx.x / 65;  // 0 = A (suffix, e^{s1-M1}), 1 = B (prefix, e^{0.01 s1})
  float M1 = dec(*m1slot);
  const float* hc = hsT + (size_t)c * NROW;
  int qb = t * 16;
  int base = br ? qb : (NROW - 16 - qb);   // 16-aligned float4 window
  float sarr[16], harr[16];
#pragma unroll
  for (int m = 0; m < 4; ++m) {
    float4 v = *(const float4*)&s1s[base + m * 4];
    sarr[m * 4] = v.x; sarr[m * 4 + 1] = v.y; sarr[m * 4 + 2] = v.z; sarr[m * 4 + 3] = v.w;
  }
  if (c < 64) {
#pragma unroll
    for (int m = 0; m < 4; ++m) {
      float4 v = *(const float4*)&hc[base + m * 4];
      harr[m * 4] = v.x; harr[m * 4 + 1] = v.y; harr[m * 4 + 2] = v.z; harr[m * 4 + 3] = v.w;
    }
  } else {
#pragma unroll
    for (int m = 0; m < 16; ++m) harr[m] = 1.0f;
  }
  float vals[16];
#pragma unroll
  for (int e = 0; e < 16; ++e) {
    int ridx = br ? e : (15 - e);
    float s = sarr[ridx];
    float w = br ? __expf(0.01f * s) : __expf(s - M1);
    vals[e] = w * harr[ridx];
  }
  float sum = 0.f;
#pragma unroll
  for (int e = 0; e < 16; ++e) sum += vals[e];
  int lane = t & 63, wid = t >> 6;
  float sc = sum;
#pragma unroll
  for (int off = 1; off < 64; off <<= 1) {
    float o = __shfl_up(sc, off);
    if (lane >= off) sc += o;
  }
  __shared__ float wt[8];
  if (lane == 63) wt[wid] = sc;
  __syncthreads();
  float woff = 0.f;
#pragma unroll
  for (int w = 0; w < 8; ++w)
    if (w < wid) woff += wt[w];
  float p = __shfl_up(sc, 1);
  float run = woff + (lane ? p : 0.f);
  if (br) {
#pragma unroll
    for (int e = 0; e < 16; ++e) {
      PreB[(size_t)(qb + e) * LD65 + c] = run;
      run += vals[e];
    }
    if (t == 511) PreB[(size_t)NROW * LD65 + c] = run;  // total
  } else {
#pragma unroll
    for (int e = 0; e < 16; ++e) {
      run += vals[e];
      SufA[(size_t)(NROW - 1 - (qb + e)) * LD65 + c] = run;
    }
    if (t == 0) SufA[(size_t)NROW * LD65 + c] = 0.f;
  }
}

// K5: per-row closed-form softmax combine + residual + W_f/lrelu + W_o.
// 256 blocks x 256 thr; each wave processes 8 rows with Wf row in registers.
__global__ __launch_bounds__(256) void k_final(const float* __restrict__ h,
    const float* __restrict__ s1s, const float* __restrict__ s2,
    const float* __restrict__ SufA, const float* __restrict__ PreB,
    const unsigned* __restrict__ m1slot, const float* __restrict__ Wf,
    const float* __restrict__ bf, const float* __restrict__ Wo,
    const float* __restrict__ bo, float* __restrict__ out) {
  int t = threadIdx.x;
  int lane = t & 63, wid = t >> 6;
  __shared__ float coarse[64];
  if (t < 64) coarse[t] = s1s[t * 128];
  __syncthreads();
  float4 wf[16];
  const float4* wrow = (const float4*)(Wf + (size_t)lane * HD);
#pragma unroll
  for (int q = 0; q < 16; ++q) wf[q] = wrow[q];
  float bfl = bf[lane], wol = Wo[lane], bo0 = bo[0];
  float M1 = dec(*m1slot);
  float myc = coarse[lane];

  for (int rr = 0; rr < 8; ++rr) {
    int i = blockIdx.x * 32 + wid * 8 + rr;
    float s2i = s2[i];
    float th = -s2i;
    float z = s2i + M1;
    float mi = lrelu(z);
    float cA = __expf(z - mi);
    float cB = __expf(0.01f * s2i - mi);
    int n1 = __popcll(__ballot(myc < th));
    int cnt = 0;
    if (n1 > 0) {
      int L = (n1 - 1) * 128;
      float v2 = s1s[L + 1 + 2 * lane];
      int n2 = __popcll(__ballot(v2 < th));
      cnt = L + 2 * n2;
      if (cnt < NROW && s1s[cnt] < th) cnt++;
    }
    const float* ra = SufA + (size_t)cnt * LD65;
    const float* rb = PreB + (size_t)cnt * LD65;
    float vA = ra[lane], vB = rb[lane];
    float zA = ra[64],  zB = rb[64];
    float Z = cA * zA + cB * zB;
    float h2 = (cA * vA + cB * vB) / Z + h[(size_t)i * HD + lane];
    float acc = bfl;
#pragma unroll
    for (int q = 0; q < 16; ++q) {
      float4 wv = wf[q];
      int c = q * 4;
      acc += wv.x * __shfl(h2, c) + wv.y * __shfl(h2, c + 1) +
             wv.z * __shfl(h2, c + 2) + wv.w * __shfl(h2, c + 3);
    }
    float h3 = lrelu(acc);
    float pv = h3 * wol;
#pragma unroll
    for (int off = 32; off > 0; off >>= 1) pv += __shfl_xor(pv, off);
    if (lane == 0) out[i] = pv + bo0;
  }
}

extern "C" void kernel_launch(void* const* d_in, const int* in_sizes, int n_in,
                              void* d_out, int out_size, void* d_ws, size_t ws_size,
                              hipStream_t stream) {
  const float* x   = (const float*)d_in[0];
  const float* Wfc = (const float*)d_in[1];
  const float* bfc = (const float*)d_in[2];
  const float* Wtr = (const float*)d_in[3];
  const float* btr = (const float*)d_in[4];
  const float* a   = (const float*)d_in[5];
  const float* Wf  = (const float*)d_in[6];
  const float* bf  = (const float*)d_in[7];
  const float* Wo  = (const float*)d_in[8];
  const float* bo  = (const float*)d_in[9];
  float* out = (float*)d_out;

  char* w = (char*)d_ws;
  size_t off = 0;
  auto alloc = [&](size_t bytes) -> void* {
    void* p = w + off;
    off = (off + bytes + 255) & ~(size_t)255;
    return p;
  };
  float* h      = (float*)alloc((size_t)NROW * HD * 4);
  float* s1     = (float*)alloc(NROW * 4);
  float* s2     = (float*)alloc(NROW * 4);
  float* u12    = (float*)alloc(130 * 4);
  unsigned* m1  = (unsigned*)alloc(4);
  int* inv      = (int*)alloc(NROW * 4);
  float* s1s    = (float*)alloc(NROW * 4);
  unsigned short* WhS = (unsigned short*)alloc((size_t)4 * NCH * 64 * 8 * 2);
  unsigned short* WlS = (unsigned short*)alloc((size_t)4 * NCH * 64 * 8 * 2);
  float* hsT    = (float*)alloc((size_t)HD * NROW * 4);
  float* SufA   = (float*)alloc((size_t)(NROW + 1) * LD65 * 4);
  float* PreB   = (float*)alloc((size_t)(NROW + 1) * LD65 * 4);
  (void)in_sizes; (void)n_in; (void)out_size; (void)ws_size;

  k_prep<<<1 + (4 * NCH * 64) / 256, 256, 0, stream>>>(Wtr, btr, a, Wfc, u12, m1, WhS, WlS);
  k_gemm<<<NROW / 16, 512, 0, stream>>>(x, WhS, WlS, bfc, u12, h, s1, s2, m1);
  k_sort<<<NROW / 32, 512, 0, stream>>>(s1, s1s, inv);
  k_trans<<<NROW / 64, 256, 0, stream>>>(h, inv, hsT);
  k_scan<<<130, 512, 0, stream>>>(s1s, hsT, m1, SufA, PreB);
  k_final<<<NROW / 32, 256, 0, stream>>>(h, s1s, s2, SufA, PreB, m1, Wf, bf, Wo, bo, out);
}